// Round 15
// baseline (308.613 us; speedup 1.0000x reference)
//
#include <hip/hip_runtime.h>
#include <hip/hip_bf16.h>

typedef __attribute__((ext_vector_type(8))) short bf16x8;
typedef __attribute__((ext_vector_type(4))) float f32x4;

__device__ inline short f2bf(float f) {
    __hip_bfloat16 h = __float2bfloat16(f);
    return *reinterpret_cast<short*>(&h);
}

// ---------------- utility ----------------

__global__ void zero_k(float* __restrict__ p, int n) {
    for (int i = blockIdx.x * blockDim.x + threadIdx.x; i < n;
         i += gridDim.x * blockDim.x)
        p[i] = 0.0f;
}

// ---------------- bucketed CSR build (no global atomics) ----------------
// pairs packed: (dst&255)<<24 | src   (src < 2^24)

__global__ __launch_bounds__(256) void bucket_hist_k(
    const int* __restrict__ dst, int* __restrict__ T, int E, int NB)
{
    __shared__ int hist[512];
    for (int b = threadIdx.x; b < NB; b += 256) hist[b] = 0;
    __syncthreads();
    int per = (E + gridDim.x - 1) / gridDim.x;
    int s = blockIdx.x * per;
    int e = min(E, s + per);
    for (int i = s + threadIdx.x; i < e; i += 256)
        atomicAdd(&hist[dst[i] >> 8], 1);
    __syncthreads();
    for (int b = threadIdx.x; b < NB; b += 256)
        T[b * gridDim.x + blockIdx.x] = hist[b];
}

__global__ __launch_bounds__(256) void scan_block_k(
    const int* __restrict__ in, int* __restrict__ out,
    int* __restrict__ bsum, int n)
{
    __shared__ int ts[256];
    int base = blockIdx.x * 2048;
    int i0 = base + threadIdx.x * 8;
    int vals[8];
    int s = 0;
#pragma unroll
    for (int j = 0; j < 8; ++j) {
        int v = (i0 + j) < n ? in[i0 + j] : 0;
        vals[j] = v; s += v;
    }
    ts[threadIdx.x] = s;
    __syncthreads();
    for (int d = 1; d < 256; d <<= 1) {
        int t = (threadIdx.x >= (unsigned)d) ? ts[threadIdx.x - d] : 0;
        __syncthreads();
        ts[threadIdx.x] += t;
        __syncthreads();
    }
    int run = ts[threadIdx.x] - s;
    if (threadIdx.x == 255) bsum[blockIdx.x] = ts[255];
#pragma unroll
    for (int j = 0; j < 8; ++j) {
        if (i0 + j < n) out[i0 + j] = run;
        run += vals[j];
    }
}

__global__ void scan_partials_k(int* __restrict__ bsum, int nb) {
    if (threadIdx.x == 0 && blockIdx.x == 0) {
        int run = 0;
        for (int i = 0; i < nb; ++i) { int t = bsum[i]; bsum[i] = run; run += t; }
    }
}

__global__ void scan_add_k(int* __restrict__ rp, const int* __restrict__ bsum,
                           int n, int E)
{
    int i = blockIdx.x * blockDim.x + threadIdx.x;
    if (i < n) rp[i] += bsum[i >> 11];
    if (i == 0) rp[n] = E;
}

__global__ __launch_bounds__(256) void bucket_scatter_k(
    const int* __restrict__ src, const int* __restrict__ dst,
    const int* __restrict__ Tsc, unsigned* __restrict__ pairs, int E, int NB)
{
    __shared__ int cur[512];
    for (int b = threadIdx.x; b < NB; b += 256)
        cur[b] = Tsc[b * gridDim.x + blockIdx.x];
    __syncthreads();
    int per = (E + gridDim.x - 1) / gridDim.x;
    int s = blockIdx.x * per;
    int e = min(E, s + per);
    for (int i = s + threadIdx.x; i < e; i += 256) {
        int d = dst[i];
        int pos = atomicAdd(&cur[d >> 8], 1);
        pairs[pos] = ((unsigned)(d & 255) << 24) | (unsigned)src[i];
    }
}

__global__ __launch_bounds__(256) void bucket_csr_k(
    const unsigned* __restrict__ pairs, const int* __restrict__ Tsc,
    int* __restrict__ row_ptr, float* __restrict__ dis,
    int* __restrict__ csr, int N, int E, int NB, int G)
{
    __shared__ int cnt[256];
    __shared__ int ts[256];
    __shared__ int cur[256];
    const int b = blockIdx.x;
    const int node0 = b << 8;
    const int e0 = Tsc[b * G];
    const int e1 = Tsc[(b + 1) * G];
    const int j = threadIdx.x;
    cnt[j] = 0;
    __syncthreads();
    for (int i = e0 + j; i < e1; i += 256)
        atomicAdd(&cnt[pairs[i] >> 24], 1);
    __syncthreads();
    int c = cnt[j];
    ts[j] = c;
    __syncthreads();
    for (int d = 1; d < 256; d <<= 1) {
        int t = (j >= d) ? ts[j - d] : 0;
        __syncthreads();
        ts[j] += t;
        __syncthreads();
    }
    int excl = ts[j] - c;
    int node = node0 + j;
    if (node < N) {
        row_ptr[node] = e0 + excl;
        dis[node] = rsqrtf(1.0f + (float)c);
    }
    cur[j] = e0 + excl;
    if (b == NB - 1 && j == 0) row_ptr[N] = E;
    __syncthreads();
    for (int i = e0 + j; i < e1; i += 256) {
        unsigned p = pairs[i];
        int pos = atomicAdd(&cur[p >> 24], 1);
        csr[pos] = (int)(p & 0xFFFFFFu);
    }
}

// ---------------- W fragment prebuild ----------------

template<int FIN, int FOUT, int NKK, int CT>
__global__ void wfrag_build_k(const float* __restrict__ W,
                              __hip_bfloat16* __restrict__ out)
{
    int idx = blockIdx.x * 256 + threadIdx.x;
    if (idx >= CT * NKK * 64 * 8) return;
    int e = idx & 7;
    int lane = (idx >> 3) & 63;
    int t = idx >> 9;
    int kk = t % NKK, nn = t / NKK;
    int col = nn * 16 + (lane & 15);
    int k = kk * 32 + (lane >> 4) * 8 + e;
    float v = (k < FIN && col < FOUT) ? W[k * FOUT + col] : 0.f;
    out[idx] = __float2bfloat16(v);
}

// ---------------- GEMM v6: MFMA, no LDS; f32 or bf16 input ----------------

template<int FIN>
__device__ inline bf16x8 load_a8f(const float* __restrict__ p, int k0) {
    bf16x8 r;
    if (k0 + 8 <= FIN) {
        float4 v0 = *reinterpret_cast<const float4*>(p + k0);
        float4 v1 = *reinterpret_cast<const float4*>(p + k0 + 4);
        r[0] = f2bf(v0.x); r[1] = f2bf(v0.y); r[2] = f2bf(v0.z); r[3] = f2bf(v0.w);
        r[4] = f2bf(v1.x); r[5] = f2bf(v1.y); r[6] = f2bf(v1.z); r[7] = f2bf(v1.w);
    } else {
#pragma unroll
        for (int e = 0; e < 8; ++e)
            r[e] = (k0 + e < FIN) ? f2bf(p[k0 + e]) : (short)0;
    }
    return r;
}

template<int FIN>
__device__ inline bf16x8 load_a8b(const __hip_bfloat16* __restrict__ p, int k0) {
    if (k0 + 8 <= FIN)
        return *reinterpret_cast<const bf16x8*>(p + k0);  // 16B aligned (stride mult of 8)
    bf16x8 r;
    const short* ps = (const short*)p;
#pragma unroll
    for (int e = 0; e < 8; ++e)
        r[e] = (k0 + e < FIN) ? ps[k0 + e] : (short)0;
    return r;
}

template<typename TIN, int FIN, int SIN, int FOUT, int HS, int NKK, int CT>
__global__ __launch_bounds__(256) void gemm_mfma_v6(
    const TIN* __restrict__ in, const __hip_bfloat16* __restrict__ wfrag,
    const float* __restrict__ dis, __hip_bfloat16* __restrict__ hh, int n)
{
    const int tid = threadIdx.x;
    const long long base = (long long)blockIdx.x * 64;
    const int cnt = (int)min((long long)64, (long long)n - base);
    const int wv = tid >> 6, lane = tid & 63;
    const int rlo = lane & 15, kg = lane >> 4, kb = kg * 8;
    const int arow = wv * 16 + rlo;
    const long long row = base + arow;

    bf16x8 a[NKK];
    if (arow < cnt) {
        const TIN* p = &in[(size_t)row * SIN];
#pragma unroll
        for (int kk = 0; kk < NKK; ++kk) {
            if constexpr (sizeof(TIN) == 4)
                a[kk] = load_a8f<FIN>((const float*)p, kk * 32 + kb);
            else
                a[kk] = load_a8b<FIN>((const __hip_bfloat16*)p, kk * 32 + kb);
        }
    } else {
#pragma unroll
        for (int kk = 0; kk < NKK; ++kk)
            a[kk] = (bf16x8){0, 0, 0, 0, 0, 0, 0, 0};
    }

    f32x4 acc[CT];
#pragma unroll
    for (int nn = 0; nn < CT; ++nn) acc[nn] = (f32x4){0.f, 0.f, 0.f, 0.f};

#pragma unroll
    for (int nn = 0; nn < CT; ++nn) {
#pragma unroll
        for (int kk = 0; kk < NKK; ++kk) {
            bf16x8 b = *reinterpret_cast<const bf16x8*>(
                &wfrag[(size_t)((nn * NKK + kk) * 64 + lane) * 8]);
            acc[nn] = __builtin_amdgcn_mfma_f32_16x16x32_bf16(a[kk], b, acc[nn], 0, 0, 0);
        }
    }

    const int r0 = wv * 16 + kg * 4;
    float dv[4];
#pragma unroll
    for (int i = 0; i < 4; ++i)
        dv[i] = (r0 + i < cnt) ? dis[base + r0 + i] : 0.f;
#pragma unroll
    for (int nn = 0; nn < CT; ++nn) {
        const int col = nn * 16 + rlo;
        if (col < FOUT) {
#pragma unroll
            for (int i = 0; i < 4; ++i) {
                int r = r0 + i;
                if (r < cnt) {
                    __hip_bfloat16 o = __float2bfloat16(acc[nn][i] * dv[i]);
                    hh[(size_t)(base + r) * HS + col] = o;
                }
            }
        }
    }
}

// ---------------- CSR aggregate v4: 16-deep MLP, optional bf16 out ----------------
// hh stride HS (bf16); out stride SO, type TOUT (float or __hip_bfloat16).

template<int F, int HS, int SO, typename TOUT>
__global__ __launch_bounds__(256) void aggregate_v4(
    const __hip_bfloat16* __restrict__ hh, const int* __restrict__ row_ptr,
    const int* __restrict__ csr, const float* __restrict__ dis,
    const float* __restrict__ b, TOUT* __restrict__ out, int n)
{
    constexpr int FG = F / 4;
    long long idx = (long long)blockIdx.x * 256 + threadIdx.x;
    if (idx >= (long long)n * FG) return;
    int node = (int)(idx / FG);
    int fg = (int)(idx - (long long)node * FG);
    const int bf = fg * 4;

    const unsigned short* hs = (const unsigned short*)hh;
    auto lo16 = [](unsigned u) { return __uint_as_float(u << 16); };
    auto hi16 = [](unsigned u) { return __uint_as_float(u & 0xFFFF0000u); };

    uint2 su = *reinterpret_cast<const uint2*>(&hs[(size_t)node * HS + bf]);
    float a0 = lo16(su.x), a1 = hi16(su.x), a2 = lo16(su.y), a3 = hi16(su.y);
    float c0 = 0.f, c1 = 0.f, c2 = 0.f, c3 = 0.f;

    int e = row_ptr[node];
    const int e1 = row_ptr[node + 1];
    for (; e + 16 <= e1; e += 16) {
        int s[16];
#pragma unroll
        for (int j = 0; j < 16; ++j) s[j] = csr[e + j];
        uint2 u[16];
#pragma unroll
        for (int j = 0; j < 16; ++j)
            u[j] = *reinterpret_cast<const uint2*>(&hs[(size_t)s[j] * HS + bf]);
#pragma unroll
        for (int j = 0; j < 16; j += 2) {
            a0 += lo16(u[j].x);     a1 += hi16(u[j].x);
            a2 += lo16(u[j].y);     a3 += hi16(u[j].y);
            c0 += lo16(u[j + 1].x); c1 += hi16(u[j + 1].x);
            c2 += lo16(u[j + 1].y); c3 += hi16(u[j + 1].y);
        }
    }
    for (; e + 4 <= e1; e += 4) {
        int s[4];
#pragma unroll
        for (int j = 0; j < 4; ++j) s[j] = csr[e + j];
        uint2 u[4];
#pragma unroll
        for (int j = 0; j < 4; ++j)
            u[j] = *reinterpret_cast<const uint2*>(&hs[(size_t)s[j] * HS + bf]);
#pragma unroll
        for (int j = 0; j < 4; j += 2) {
            a0 += lo16(u[j].x);     a1 += hi16(u[j].x);
            a2 += lo16(u[j].y);     a3 += hi16(u[j].y);
            c0 += lo16(u[j + 1].x); c1 += hi16(u[j + 1].x);
            c2 += lo16(u[j + 1].y); c3 += hi16(u[j + 1].y);
        }
    }
    for (; e < e1; ++e) {
        int s = csr[e];
        uint2 u = *reinterpret_cast<const uint2*>(&hs[(size_t)s * HS + bf]);
        a0 += lo16(u.x); a1 += hi16(u.x); a2 += lo16(u.y); a3 += hi16(u.y);
    }
    a0 += c0; a1 += c1; a2 += c2; a3 += c3;

    float d = dis[node];
    float4 bb = *reinterpret_cast<const float4*>(&b[bf]);
    float r0 = fmaxf(fmaf(d, a0, bb.x), 0.0f);
    float r1 = fmaxf(fmaf(d, a1, bb.y), 0.0f);
    float r2 = fmaxf(fmaf(d, a2, bb.z), 0.0f);
    float r3 = fmaxf(fmaf(d, a3, bb.w), 0.0f);

    if constexpr (sizeof(TOUT) == 2) {
        alignas(8) __hip_bfloat16 o[4];
        o[0] = __float2bfloat16(r0);
        o[1] = __float2bfloat16(r1);
        o[2] = __float2bfloat16(r2);
        o[3] = __float2bfloat16(r3);
        *reinterpret_cast<uint2*>(&((__hip_bfloat16*)out)[(size_t)node * SO + bf]) =
            *reinterpret_cast<const uint2*>(o);
    } else {
        float4 o;
        o.x = r0; o.y = r1; o.z = r2; o.w = r3;
        *reinterpret_cast<float4*>(&((float*)out)[(size_t)node * SO + bf]) = o;
    }
}

// ---------------- pooling ----------------

__global__ __launch_bounds__(256) void pool2_k(
    const float* __restrict__ h, const int* __restrict__ batch,
    float* __restrict__ sums, float* __restrict__ cnt, int n)
{
    constexpr int CHUNK = 1024;
    __shared__ float s[64 * 32];
    __shared__ float sc[64];
    for (int i = threadIdx.x; i < 64 * 32; i += 256) s[i] = 0.0f;
    if (threadIdx.x < 64) sc[threadIdx.x] = 0.0f;
    __syncthreads();

    long long start = (long long)blockIdx.x * CHUNK;
    long long end = start + CHUNK < n ? start + CHUNK : n;
    int total = (int)(end - start) * 32;
    for (int i = threadIdx.x; i < total; i += 256) {
        int r = i >> 5;
        int f = i & 31;
        int node = (int)start + r;
        int g = batch[node];
        atomicAdd(&s[g * 32 + f], h[(size_t)node * 32 + f]);
        if (f == 0) atomicAdd(&sc[g], 1.0f);
    }
    __syncthreads();
    for (int i = threadIdx.x; i < 64 * 32; i += 256) {
        float v = s[i];
        if (v != 0.0f) atomicAdd(&sums[i], v);
    }
    if (threadIdx.x < 64) {
        float v = sc[threadIdx.x];
        if (v != 0.0f) atomicAdd(&cnt[threadIdx.x], v);
    }
}

__global__ void head_k(const float* __restrict__ sums, const float* __restrict__ cnt,
                       const float* __restrict__ Wl, const float* __restrict__ bl,
                       float* __restrict__ out)
{
    int tid = threadIdx.x;
    if (tid < 128) {
        int g = tid >> 1;
        int o = tid & 1;
        float c = fmaxf(cnt[g], 1.0f);
        float a = 0.0f;
#pragma unroll
        for (int f = 0; f < 32; ++f)
            a += (sums[g * 32 + f] / c) * Wl[f * 2 + o];
        out[tid] = a + bl[o];
    }
}

// ---------------- launch ----------------

extern "C" void kernel_launch(void* const* d_in, const int* in_sizes, int n_in,
                              void* d_out, int out_size, void* d_ws, size_t ws_size,
                              hipStream_t stream)
{
    const float* x   = (const float*)d_in[0];
    const int*   ei  = (const int*)d_in[1];
    const int*   bat = (const int*)d_in[2];
    const float* W1  = (const float*)d_in[3];
    const float* b1  = (const float*)d_in[4];
    const float* W2  = (const float*)d_in[5];
    const float* b2  = (const float*)d_in[6];
    const float* W3  = (const float*)d_in[7];
    const float* b3  = (const float*)d_in[8];
    const float* Wl  = (const float*)d_in[9];
    const float* bl  = (const float*)d_in[10];

    const int N = in_sizes[0] / 128;
    const int E = in_sizes[1] / 2;
    const int* src = ei;
    const int* dst = ei + E;

    const int NB = (N + 255) >> 8;
    const int G  = 128;
    const int NBG = NB * G;

    char* ws = (char*)d_ws;
    size_t off = 0;
    auto alloc = [&](size_t bytes) -> char* {
        char* p = ws + off;
        off += (bytes + 255) & ~(size_t)255;
        return p;
    };
    float* dis     = (float*)alloc((size_t)N * 4);
    int*   row_ptr = (int*)  alloc((size_t)(N + 1) * 4);
    int*   bsum    = (int*)  alloc(256 * 4);
    int*   csr     = (int*)  alloc((size_t)E * 4);
    int*   T       = (int*)  alloc((size_t)NBG * 4);
    int*   Tsc     = (int*)  alloc((size_t)(NBG + 1) * 4);
    __hip_bfloat16* WF1 = (__hip_bfloat16*)alloc(6 * 4 * 512 * 2);
    __hip_bfloat16* WF2 = (__hip_bfloat16*)alloc(4 * 3 * 512 * 2);
    __hip_bfloat16* WF3 = (__hip_bfloat16*)alloc(2 * 2 * 512 * 2);
    __hip_bfloat16* A = (__hip_bfloat16*)alloc((size_t)N * 96 * 2);  // hh, stride<=96
    __hip_bfloat16* B = (__hip_bfloat16*)alloc((size_t)N * 96 * 2);  // L1 out bf16 s96 / L3 out f32 s32
    __hip_bfloat16* C = (__hip_bfloat16*)alloc((size_t)N * 64 * 2);  // L2 out bf16 s64
    float* D       = (float*)alloc((size_t)(64 * 32 + 64) * 4);
    unsigned* pairs = (unsigned*)C;  // overlay, prologue only (E*4 <= N*64*2)

    dim3 blk(256);
    auto cdiv = [](long long a, long long b) { return (int)((a + b - 1) / b); };

    // ---- W fragment prebuild ----
    wfrag_build_k<128, 84, 4, 6><<<cdiv(6 * 4 * 512, 256), blk, 0, stream>>>(W1, WF1);
    wfrag_build_k< 84, 64, 3, 4><<<cdiv(4 * 3 * 512, 256), blk, 0, stream>>>(W2, WF2);
    wfrag_build_k< 64, 32, 2, 2><<<cdiv(2 * 2 * 512, 256), blk, 0, stream>>>(W3, WF3);

    // ---- bucketed CSR build ----
    bucket_hist_k<<<G, blk, 0, stream>>>(dst, T, E, NB);
    int nb_scan = cdiv(NBG, 2048);
    scan_block_k<<<nb_scan, blk, 0, stream>>>(T, Tsc, bsum, NBG);
    scan_partials_k<<<1, 64, 0, stream>>>(bsum, nb_scan);
    scan_add_k<<<cdiv(NBG, 256), blk, 0, stream>>>(Tsc, bsum, NBG, E);
    bucket_scatter_k<<<G, blk, 0, stream>>>(src, dst, Tsc, pairs, E, NB);
    bucket_csr_k<<<NB, blk, 0, stream>>>(pairs, Tsc, row_ptr, dis, csr, N, E, NB, G);

    // Layer 1: 128 -> 84 (hh stride 96; out B bf16 stride 96)
    gemm_mfma_v6<float, 128, 128, 84, 96, 4, 6><<<cdiv(N, 64), blk, 0, stream>>>(x, WF1, dis, A, N);
    aggregate_v4<84, 96, 96, __hip_bfloat16><<<cdiv((long long)N * 21, 256), blk, 0, stream>>>(
        A, row_ptr, csr, dis, b1, B, N);

    // Layer 2: 84 -> 64 (in B bf16 stride 96; hh stride 64; out C bf16 stride 64)
    gemm_mfma_v6<__hip_bfloat16, 84, 96, 64, 64, 3, 4><<<cdiv(N, 64), blk, 0, stream>>>(B, WF2, dis, A, N);
    aggregate_v4<64, 64, 64, __hip_bfloat16><<<cdiv((long long)N * 16, 256), blk, 0, stream>>>(
        A, row_ptr, csr, dis, b2, C, N);

    // Layer 3: 64 -> 32 (in C bf16 stride 64; hh stride 32; out B f32 stride 32)
    gemm_mfma_v6<__hip_bfloat16, 64, 64, 32, 32, 2, 2><<<cdiv(N, 64), blk, 0, stream>>>(C, WF3, dis, A, N);
    aggregate_v4<32, 32, 32, float><<<cdiv((long long)N * 8, 256), blk, 0, stream>>>(
        A, row_ptr, csr, dis, b3, (float*)B, N);

    // global mean pool + head
    zero_k<<<cdiv(64 * 32 + 64, 256), blk, 0, stream>>>(D, 64 * 32 + 64);
    pool2_k<<<cdiv(N, 1024), blk, 0, stream>>>((float*)B, bat, D, D + 64 * 32, N);
    head_k<<<1, 128, 0, stream>>>(D, D + 64 * 32, Wl, bl, (float*)d_out);
}

// Round 16
// 288.821 us; speedup vs baseline: 1.0685x; 1.0685x over previous
//
#include <hip/hip_runtime.h>
#include <hip/hip_bf16.h>

typedef __attribute__((ext_vector_type(8))) short bf16x8;
typedef __attribute__((ext_vector_type(4))) float f32x4;

__device__ inline short f2bf(float f) {
    __hip_bfloat16 h = __float2bfloat16(f);
    return *reinterpret_cast<short*>(&h);
}

// ---------------- utility ----------------

__global__ void zero_k(float* __restrict__ p, int n) {
    for (int i = blockIdx.x * blockDim.x + threadIdx.x; i < n;
         i += gridDim.x * blockDim.x)
        p[i] = 0.0f;
}

// ---------------- bucketed CSR build (no global atomics) ----------------
// pairs packed: (dst&255)<<24 | src   (src < 2^24)

__global__ __launch_bounds__(256) void bucket_hist_k(
    const int* __restrict__ dst, int* __restrict__ T, int E, int NB)
{
    __shared__ int hist[512];
    for (int b = threadIdx.x; b < NB; b += 256) hist[b] = 0;
    __syncthreads();
    int per = (E + gridDim.x - 1) / gridDim.x;
    int s = blockIdx.x * per;
    int e = min(E, s + per);
    for (int i = s + threadIdx.x; i < e; i += 256)
        atomicAdd(&hist[dst[i] >> 8], 1);
    __syncthreads();
    for (int b = threadIdx.x; b < NB; b += 256)
        T[b * gridDim.x + blockIdx.x] = hist[b];
}

__global__ __launch_bounds__(256) void scan_block_k(
    const int* __restrict__ in, int* __restrict__ out,
    int* __restrict__ bsum, int n)
{
    __shared__ int ts[256];
    int base = blockIdx.x * 2048;
    int i0 = base + threadIdx.x * 8;
    int vals[8];
    int s = 0;
#pragma unroll
    for (int j = 0; j < 8; ++j) {
        int v = (i0 + j) < n ? in[i0 + j] : 0;
        vals[j] = v; s += v;
    }
    ts[threadIdx.x] = s;
    __syncthreads();
    for (int d = 1; d < 256; d <<= 1) {
        int t = (threadIdx.x >= (unsigned)d) ? ts[threadIdx.x - d] : 0;
        __syncthreads();
        ts[threadIdx.x] += t;
        __syncthreads();
    }
    int run = ts[threadIdx.x] - s;
    if (threadIdx.x == 255) bsum[blockIdx.x] = ts[255];
#pragma unroll
    for (int j = 0; j < 8; ++j) {
        if (i0 + j < n) out[i0 + j] = run;
        run += vals[j];
    }
}

__global__ void scan_partials_k(int* __restrict__ bsum, int nb) {
    if (threadIdx.x == 0 && blockIdx.x == 0) {
        int run = 0;
        for (int i = 0; i < nb; ++i) { int t = bsum[i]; bsum[i] = run; run += t; }
    }
}

__global__ void scan_add_k(int* __restrict__ rp, const int* __restrict__ bsum,
                           int n, int E)
{
    int i = blockIdx.x * blockDim.x + threadIdx.x;
    if (i < n) rp[i] += bsum[i >> 11];
    if (i == 0) rp[n] = E;
}

__global__ __launch_bounds__(256) void bucket_scatter_k(
    const int* __restrict__ src, const int* __restrict__ dst,
    const int* __restrict__ Tsc, unsigned* __restrict__ pairs, int E, int NB)
{
    __shared__ int cur[512];
    for (int b = threadIdx.x; b < NB; b += 256)
        cur[b] = Tsc[b * gridDim.x + blockIdx.x];
    __syncthreads();
    int per = (E + gridDim.x - 1) / gridDim.x;
    int s = blockIdx.x * per;
    int e = min(E, s + per);
    for (int i = s + threadIdx.x; i < e; i += 256) {
        int d = dst[i];
        int pos = atomicAdd(&cur[d >> 8], 1);
        pairs[pos] = ((unsigned)(d & 255) << 24) | (unsigned)src[i];
    }
}

__global__ __launch_bounds__(256) void bucket_csr_k(
    const unsigned* __restrict__ pairs, const int* __restrict__ Tsc,
    int* __restrict__ row_ptr, float* __restrict__ dis,
    int* __restrict__ csr, int N, int E, int NB, int G)
{
    __shared__ int cnt[256];
    __shared__ int ts[256];
    __shared__ int cur[256];
    const int b = blockIdx.x;
    const int node0 = b << 8;
    const int e0 = Tsc[b * G];
    const int e1 = Tsc[(b + 1) * G];
    const int j = threadIdx.x;
    cnt[j] = 0;
    __syncthreads();
    for (int i = e0 + j; i < e1; i += 256)
        atomicAdd(&cnt[pairs[i] >> 24], 1);
    __syncthreads();
    int c = cnt[j];
    ts[j] = c;
    __syncthreads();
    for (int d = 1; d < 256; d <<= 1) {
        int t = (j >= d) ? ts[j - d] : 0;
        __syncthreads();
        ts[j] += t;
        __syncthreads();
    }
    int excl = ts[j] - c;
    int node = node0 + j;
    if (node < N) {
        row_ptr[node] = e0 + excl;
        dis[node] = rsqrtf(1.0f + (float)c);
    }
    cur[j] = e0 + excl;
    if (b == NB - 1 && j == 0) row_ptr[N] = E;
    __syncthreads();
    for (int i = e0 + j; i < e1; i += 256) {
        unsigned p = pairs[i];
        int pos = atomicAdd(&cur[p >> 24], 1);
        csr[pos] = (int)(p & 0xFFFFFFu);
    }
}

// ---------------- W fragment prebuild ----------------

template<int FIN, int FOUT, int NKK, int CT>
__global__ void wfrag_build_k(const float* __restrict__ W,
                              __hip_bfloat16* __restrict__ out)
{
    int idx = blockIdx.x * 256 + threadIdx.x;
    if (idx >= CT * NKK * 64 * 8) return;
    int e = idx & 7;
    int lane = (idx >> 3) & 63;
    int t = idx >> 9;
    int kk = t % NKK, nn = t / NKK;
    int col = nn * 16 + (lane & 15);
    int k = kk * 32 + (lane >> 4) * 8 + e;
    float v = (k < FIN && col < FOUT) ? W[k * FOUT + col] : 0.f;
    out[idx] = __float2bfloat16(v);
}

// ---------------- GEMM v6: MFMA, no LDS; f32 or bf16 input ----------------

template<int FIN>
__device__ inline bf16x8 load_a8f(const float* __restrict__ p, int k0) {
    bf16x8 r;
    if (k0 + 8 <= FIN) {
        float4 v0 = *reinterpret_cast<const float4*>(p + k0);
        float4 v1 = *reinterpret_cast<const float4*>(p + k0 + 4);
        r[0] = f2bf(v0.x); r[1] = f2bf(v0.y); r[2] = f2bf(v0.z); r[3] = f2bf(v0.w);
        r[4] = f2bf(v1.x); r[5] = f2bf(v1.y); r[6] = f2bf(v1.z); r[7] = f2bf(v1.w);
    } else {
#pragma unroll
        for (int e = 0; e < 8; ++e)
            r[e] = (k0 + e < FIN) ? f2bf(p[k0 + e]) : (short)0;
    }
    return r;
}

template<int FIN>
__device__ inline bf16x8 load_a8b(const __hip_bfloat16* __restrict__ p, int k0) {
    if (k0 + 8 <= FIN)
        return *reinterpret_cast<const bf16x8*>(p + k0);
    bf16x8 r;
    const short* ps = (const short*)p;
#pragma unroll
    for (int e = 0; e < 8; ++e)
        r[e] = (k0 + e < FIN) ? ps[k0 + e] : (short)0;
    return r;
}

template<typename TIN, int FIN, int SIN, int FOUT, int HS, int NKK, int CT>
__global__ __launch_bounds__(256) void gemm_mfma_v6(
    const TIN* __restrict__ in, const __hip_bfloat16* __restrict__ wfrag,
    const float* __restrict__ dis, __hip_bfloat16* __restrict__ hh, int n)
{
    const int tid = threadIdx.x;
    const long long base = (long long)blockIdx.x * 64;
    const int cnt = (int)min((long long)64, (long long)n - base);
    const int wv = tid >> 6, lane = tid & 63;
    const int rlo = lane & 15, kg = lane >> 4, kb = kg * 8;
    const int arow = wv * 16 + rlo;
    const long long row = base + arow;

    bf16x8 a[NKK];
    if (arow < cnt) {
        const TIN* p = &in[(size_t)row * SIN];
#pragma unroll
        for (int kk = 0; kk < NKK; ++kk) {
            if constexpr (sizeof(TIN) == 4)
                a[kk] = load_a8f<FIN>((const float*)p, kk * 32 + kb);
            else
                a[kk] = load_a8b<FIN>((const __hip_bfloat16*)p, kk * 32 + kb);
        }
    } else {
#pragma unroll
        for (int kk = 0; kk < NKK; ++kk)
            a[kk] = (bf16x8){0, 0, 0, 0, 0, 0, 0, 0};
    }

    f32x4 acc[CT];
#pragma unroll
    for (int nn = 0; nn < CT; ++nn) acc[nn] = (f32x4){0.f, 0.f, 0.f, 0.f};

#pragma unroll
    for (int nn = 0; nn < CT; ++nn) {
#pragma unroll
        for (int kk = 0; kk < NKK; ++kk) {
            bf16x8 b = *reinterpret_cast<const bf16x8*>(
                &wfrag[(size_t)((nn * NKK + kk) * 64 + lane) * 8]);
            acc[nn] = __builtin_amdgcn_mfma_f32_16x16x32_bf16(a[kk], b, acc[nn], 0, 0, 0);
        }
    }

    const int r0 = wv * 16 + kg * 4;
    float dv[4];
#pragma unroll
    for (int i = 0; i < 4; ++i)
        dv[i] = (r0 + i < cnt) ? dis[base + r0 + i] : 0.f;
#pragma unroll
    for (int nn = 0; nn < CT; ++nn) {
        const int col = nn * 16 + rlo;
        if (col < FOUT) {
#pragma unroll
            for (int i = 0; i < 4; ++i) {
                int r = r0 + i;
                if (r < cnt) {
                    __hip_bfloat16 o = __float2bfloat16(acc[nn][i] * dv[i]);
                    hh[(size_t)(base + r) * HS + col] = o;
                }
            }
        }
    }
}

// ---------------- CSR aggregate v5: 8-deep MLP (proven), strided, bf16/f32 out --------

template<int F, int HS, int SO, typename TOUT>
__global__ __launch_bounds__(256) void aggregate_v5(
    const __hip_bfloat16* __restrict__ hh, const int* __restrict__ row_ptr,
    const int* __restrict__ csr, const float* __restrict__ dis,
    const float* __restrict__ b, TOUT* __restrict__ out, int n)
{
    constexpr int FG = F / 4;
    long long idx = (long long)blockIdx.x * 256 + threadIdx.x;
    if (idx >= (long long)n * FG) return;
    int node = (int)(idx / FG);
    int fg = (int)(idx - (long long)node * FG);
    const int bf = fg * 4;

    const unsigned short* hs = (const unsigned short*)hh;
    auto lo16 = [](unsigned u) { return __uint_as_float(u << 16); };
    auto hi16 = [](unsigned u) { return __uint_as_float(u & 0xFFFF0000u); };

    uint2 su = *reinterpret_cast<const uint2*>(&hs[(size_t)node * HS + bf]);
    float a0 = lo16(su.x), a1 = hi16(su.x), a2 = lo16(su.y), a3 = hi16(su.y);
    float c0 = 0.f, c1 = 0.f, c2 = 0.f, c3 = 0.f;

    int e = row_ptr[node];
    const int e1 = row_ptr[node + 1];
    for (; e + 8 <= e1; e += 8) {
        int s0 = csr[e],     s1 = csr[e + 1], s2 = csr[e + 2], s3 = csr[e + 3];
        int s4 = csr[e + 4], s5 = csr[e + 5], s6 = csr[e + 6], s7 = csr[e + 7];
        uint2 u0 = *reinterpret_cast<const uint2*>(&hs[(size_t)s0 * HS + bf]);
        uint2 u1 = *reinterpret_cast<const uint2*>(&hs[(size_t)s1 * HS + bf]);
        uint2 u2 = *reinterpret_cast<const uint2*>(&hs[(size_t)s2 * HS + bf]);
        uint2 u3 = *reinterpret_cast<const uint2*>(&hs[(size_t)s3 * HS + bf]);
        uint2 u4 = *reinterpret_cast<const uint2*>(&hs[(size_t)s4 * HS + bf]);
        uint2 u5 = *reinterpret_cast<const uint2*>(&hs[(size_t)s5 * HS + bf]);
        uint2 u6 = *reinterpret_cast<const uint2*>(&hs[(size_t)s6 * HS + bf]);
        uint2 u7 = *reinterpret_cast<const uint2*>(&hs[(size_t)s7 * HS + bf]);
        a0 += lo16(u0.x); a1 += hi16(u0.x); a2 += lo16(u0.y); a3 += hi16(u0.y);
        c0 += lo16(u1.x); c1 += hi16(u1.x); c2 += lo16(u1.y); c3 += hi16(u1.y);
        a0 += lo16(u2.x); a1 += hi16(u2.x); a2 += lo16(u2.y); a3 += hi16(u2.y);
        c0 += lo16(u3.x); c1 += hi16(u3.x); c2 += lo16(u3.y); c3 += hi16(u3.y);
        a0 += lo16(u4.x); a1 += hi16(u4.x); a2 += lo16(u4.y); a3 += hi16(u4.y);
        c0 += lo16(u5.x); c1 += hi16(u5.x); c2 += lo16(u5.y); c3 += hi16(u5.y);
        a0 += lo16(u6.x); a1 += hi16(u6.x); a2 += lo16(u6.y); a3 += hi16(u6.y);
        c0 += lo16(u7.x); c1 += hi16(u7.x); c2 += lo16(u7.y); c3 += hi16(u7.y);
    }
    if (e + 4 <= e1) {
        int s0 = csr[e], s1 = csr[e + 1], s2 = csr[e + 2], s3 = csr[e + 3];
        uint2 u0 = *reinterpret_cast<const uint2*>(&hs[(size_t)s0 * HS + bf]);
        uint2 u1 = *reinterpret_cast<const uint2*>(&hs[(size_t)s1 * HS + bf]);
        uint2 u2 = *reinterpret_cast<const uint2*>(&hs[(size_t)s2 * HS + bf]);
        uint2 u3 = *reinterpret_cast<const uint2*>(&hs[(size_t)s3 * HS + bf]);
        a0 += lo16(u0.x); a1 += hi16(u0.x); a2 += lo16(u0.y); a3 += hi16(u0.y);
        c0 += lo16(u1.x); c1 += hi16(u1.x); c2 += lo16(u1.y); c3 += hi16(u1.y);
        a0 += lo16(u2.x); a1 += hi16(u2.x); a2 += lo16(u2.y); a3 += hi16(u2.y);
        c0 += lo16(u3.x); c1 += hi16(u3.x); c2 += lo16(u3.y); c3 += hi16(u3.y);
        e += 4;
    }
    for (; e < e1; ++e) {
        int s = csr[e];
        uint2 u = *reinterpret_cast<const uint2*>(&hs[(size_t)s * HS + bf]);
        a0 += lo16(u.x); a1 += hi16(u.x); a2 += lo16(u.y); a3 += hi16(u.y);
    }
    a0 += c0; a1 += c1; a2 += c2; a3 += c3;

    float d = dis[node];
    float4 bb = *reinterpret_cast<const float4*>(&b[bf]);
    float r0 = fmaxf(fmaf(d, a0, bb.x), 0.0f);
    float r1 = fmaxf(fmaf(d, a1, bb.y), 0.0f);
    float r2 = fmaxf(fmaf(d, a2, bb.z), 0.0f);
    float r3 = fmaxf(fmaf(d, a3, bb.w), 0.0f);

    if constexpr (sizeof(TOUT) == 2) {
        alignas(8) __hip_bfloat16 o[4];
        o[0] = __float2bfloat16(r0);
        o[1] = __float2bfloat16(r1);
        o[2] = __float2bfloat16(r2);
        o[3] = __float2bfloat16(r3);
        *reinterpret_cast<uint2*>(&((__hip_bfloat16*)out)[(size_t)node * SO + bf]) =
            *reinterpret_cast<const uint2*>(o);
    } else {
        float4 o;
        o.x = r0; o.y = r1; o.z = r2; o.w = r3;
        *reinterpret_cast<float4*>(&((float*)out)[(size_t)node * SO + bf]) = o;
    }
}

// ---------------- pooling ----------------

__global__ __launch_bounds__(256) void pool2_k(
    const float* __restrict__ h, const int* __restrict__ batch,
    float* __restrict__ sums, float* __restrict__ cnt, int n)
{
    constexpr int CHUNK = 1024;
    __shared__ float s[64 * 32];
    __shared__ float sc[64];
    for (int i = threadIdx.x; i < 64 * 32; i += 256) s[i] = 0.0f;
    if (threadIdx.x < 64) sc[threadIdx.x] = 0.0f;
    __syncthreads();

    long long start = (long long)blockIdx.x * CHUNK;
    long long end = start + CHUNK < n ? start + CHUNK : n;
    int total = (int)(end - start) * 32;
    for (int i = threadIdx.x; i < total; i += 256) {
        int r = i >> 5;
        int f = i & 31;
        int node = (int)start + r;
        int g = batch[node];
        atomicAdd(&s[g * 32 + f], h[(size_t)node * 32 + f]);
        if (f == 0) atomicAdd(&sc[g], 1.0f);
    }
    __syncthreads();
    for (int i = threadIdx.x; i < 64 * 32; i += 256) {
        float v = s[i];
        if (v != 0.0f) atomicAdd(&sums[i], v);
    }
    if (threadIdx.x < 64) {
        float v = sc[threadIdx.x];
        if (v != 0.0f) atomicAdd(&cnt[threadIdx.x], v);
    }
}

__global__ void head_k(const float* __restrict__ sums, const float* __restrict__ cnt,
                       const float* __restrict__ Wl, const float* __restrict__ bl,
                       float* __restrict__ out)
{
    int tid = threadIdx.x;
    if (tid < 128) {
        int g = tid >> 1;
        int o = tid & 1;
        float c = fmaxf(cnt[g], 1.0f);
        float a = 0.0f;
#pragma unroll
        for (int f = 0; f < 32; ++f)
            a += (sums[g * 32 + f] / c) * Wl[f * 2 + o];
        out[tid] = a + bl[o];
    }
}

// ---------------- launch ----------------

extern "C" void kernel_launch(void* const* d_in, const int* in_sizes, int n_in,
                              void* d_out, int out_size, void* d_ws, size_t ws_size,
                              hipStream_t stream)
{
    const float* x   = (const float*)d_in[0];
    const int*   ei  = (const int*)d_in[1];
    const int*   bat = (const int*)d_in[2];
    const float* W1  = (const float*)d_in[3];
    const float* b1  = (const float*)d_in[4];
    const float* W2  = (const float*)d_in[5];
    const float* b2  = (const float*)d_in[6];
    const float* W3  = (const float*)d_in[7];
    const float* b3  = (const float*)d_in[8];
    const float* Wl  = (const float*)d_in[9];
    const float* bl  = (const float*)d_in[10];

    const int N = in_sizes[0] / 128;
    const int E = in_sizes[1] / 2;
    const int* src = ei;
    const int* dst = ei + E;

    const int NB = (N + 255) >> 8;
    const int G  = 128;
    const int NBG = NB * G;

    char* ws = (char*)d_ws;
    size_t off = 0;
    auto alloc = [&](size_t bytes) -> char* {
        char* p = ws + off;
        off += (bytes + 255) & ~(size_t)255;
        return p;
    };
    float* dis     = (float*)alloc((size_t)N * 4);
    int*   row_ptr = (int*)  alloc((size_t)(N + 1) * 4);
    int*   bsum    = (int*)  alloc(256 * 4);
    int*   csr     = (int*)  alloc((size_t)E * 4);
    int*   T       = (int*)  alloc((size_t)NBG * 4);
    int*   Tsc     = (int*)  alloc((size_t)(NBG + 1) * 4);
    __hip_bfloat16* WF1 = (__hip_bfloat16*)alloc(6 * 4 * 512 * 2);
    __hip_bfloat16* WF2 = (__hip_bfloat16*)alloc(4 * 3 * 512 * 2);
    __hip_bfloat16* WF3 = (__hip_bfloat16*)alloc(2 * 2 * 512 * 2);
    __hip_bfloat16* A = (__hip_bfloat16*)alloc((size_t)N * 96 * 2);
    __hip_bfloat16* B = (__hip_bfloat16*)alloc((size_t)N * 96 * 2);
    __hip_bfloat16* C = (__hip_bfloat16*)alloc((size_t)N * 64 * 2);
    float* D       = (float*)alloc((size_t)(64 * 32 + 64) * 4);
    unsigned* pairs = (unsigned*)C;  // overlay, prologue only

    dim3 blk(256);
    auto cdiv = [](long long a, long long b) { return (int)((a + b - 1) / b); };

    // ---- W fragment prebuild ----
    wfrag_build_k<128, 84, 4, 6><<<cdiv(6 * 4 * 512, 256), blk, 0, stream>>>(W1, WF1);
    wfrag_build_k< 84, 64, 3, 4><<<cdiv(4 * 3 * 512, 256), blk, 0, stream>>>(W2, WF2);
    wfrag_build_k< 64, 32, 2, 2><<<cdiv(2 * 2 * 512, 256), blk, 0, stream>>>(W3, WF3);

    // ---- bucketed CSR build ----
    bucket_hist_k<<<G, blk, 0, stream>>>(dst, T, E, NB);
    int nb_scan = cdiv(NBG, 2048);
    scan_block_k<<<nb_scan, blk, 0, stream>>>(T, Tsc, bsum, NBG);
    scan_partials_k<<<1, 64, 0, stream>>>(bsum, nb_scan);
    scan_add_k<<<cdiv(NBG, 256), blk, 0, stream>>>(Tsc, bsum, NBG, E);
    bucket_scatter_k<<<G, blk, 0, stream>>>(src, dst, Tsc, pairs, E, NB);
    bucket_csr_k<<<NB, blk, 0, stream>>>(pairs, Tsc, row_ptr, dis, csr, N, E, NB, G);

    // Layer 1: 128 -> 84 (hh stride 96; out B bf16 stride 96)
    gemm_mfma_v6<float, 128, 128, 84, 96, 4, 6><<<cdiv(N, 64), blk, 0, stream>>>(x, WF1, dis, A, N);
    aggregate_v5<84, 96, 96, __hip_bfloat16><<<cdiv((long long)N * 21, 256), blk, 0, stream>>>(
        A, row_ptr, csr, dis, b1, B, N);

    // Layer 2: 84 -> 64 (in B bf16 stride 96; hh stride 64; out C bf16 stride 64)
    gemm_mfma_v6<__hip_bfloat16, 84, 96, 64, 64, 3, 4><<<cdiv(N, 64), blk, 0, stream>>>(B, WF2, dis, A, N);
    aggregate_v5<64, 64, 64, __hip_bfloat16><<<cdiv((long long)N * 16, 256), blk, 0, stream>>>(
        A, row_ptr, csr, dis, b2, C, N);

    // Layer 3: 64 -> 32 (in C bf16 stride 64; hh stride 32; out B f32 stride 32)
    gemm_mfma_v6<__hip_bfloat16, 64, 64, 32, 32, 2, 2><<<cdiv(N, 64), blk, 0, stream>>>(C, WF3, dis, A, N);
    aggregate_v5<32, 32, 32, float><<<cdiv((long long)N * 8, 256), blk, 0, stream>>>(
        A, row_ptr, csr, dis, b3, (float*)B, N);

    // global mean pool + head
    zero_k<<<cdiv(64 * 32 + 64, 256), blk, 0, stream>>>(D, 64 * 32 + 64);
    pool2_k<<<cdiv(N, 1024), blk, 0, stream>>>((float*)B, bat, D, D + 64 * 32, N);
    head_k<<<1, 128, 0, stream>>>(D, D + 64 * 32, Wl, bl, (float*)d_out);
}

// Round 17
// 267.960 us; speedup vs baseline: 1.1517x; 1.0779x over previous
//
#include <hip/hip_runtime.h>
#include <hip/hip_bf16.h>

typedef __attribute__((ext_vector_type(8))) short bf16x8;
typedef __attribute__((ext_vector_type(4))) float f32x4;

__device__ inline short f2bf(float f) {
    __hip_bfloat16 h = __float2bfloat16(f);
    return *reinterpret_cast<short*>(&h);
}

// ---------------- bucketed CSR build (no global atomics) ----------------
// pairs packed: (dst&255)<<24 | src   (src < 2^24)

__global__ __launch_bounds__(256) void bucket_hist_k(
    const int* __restrict__ dst, int* __restrict__ T, int E, int NB)
{
    __shared__ int hist[512];
    for (int b = threadIdx.x; b < NB; b += 256) hist[b] = 0;
    __syncthreads();
    int per = (E + gridDim.x - 1) / gridDim.x;
    int s = blockIdx.x * per;
    int e = min(E, s + per);
    for (int i = s + threadIdx.x; i < e; i += 256)
        atomicAdd(&hist[dst[i] >> 8], 1);
    __syncthreads();
    for (int b = threadIdx.x; b < NB; b += 256)
        T[b * gridDim.x + blockIdx.x] = hist[b];
}

__global__ __launch_bounds__(256) void scan_block_k(
    const int* __restrict__ in, int* __restrict__ out,
    int* __restrict__ bsum, int n)
{
    __shared__ int ts[256];
    int base = blockIdx.x * 2048;
    int i0 = base + threadIdx.x * 8;
    int vals[8];
    int s = 0;
#pragma unroll
    for (int j = 0; j < 8; ++j) {
        int v = (i0 + j) < n ? in[i0 + j] : 0;
        vals[j] = v; s += v;
    }
    ts[threadIdx.x] = s;
    __syncthreads();
    for (int d = 1; d < 256; d <<= 1) {
        int t = (threadIdx.x >= (unsigned)d) ? ts[threadIdx.x - d] : 0;
        __syncthreads();
        ts[threadIdx.x] += t;
        __syncthreads();
    }
    int run = ts[threadIdx.x] - s;
    if (threadIdx.x == 255) bsum[blockIdx.x] = ts[255];
#pragma unroll
    for (int j = 0; j < 8; ++j) {
        if (i0 + j < n) out[i0 + j] = run;
        run += vals[j];
    }
}

__global__ void scan_partials_k(int* __restrict__ bsum, int nb) {
    if (threadIdx.x == 0 && blockIdx.x == 0) {
        int run = 0;
        for (int i = 0; i < nb; ++i) { int t = bsum[i]; bsum[i] = run; run += t; }
    }
}

__global__ void scan_add_k(int* __restrict__ rp, const int* __restrict__ bsum,
                           int n, int E)
{
    int i = blockIdx.x * blockDim.x + threadIdx.x;
    if (i < n) rp[i] += bsum[i >> 11];
    if (i == 0) rp[n] = E;
}

__global__ __launch_bounds__(256) void bucket_scatter_k(
    const int* __restrict__ src, const int* __restrict__ dst,
    const int* __restrict__ Tsc, unsigned* __restrict__ pairs, int E, int NB)
{
    __shared__ int cur[512];
    for (int b = threadIdx.x; b < NB; b += 256)
        cur[b] = Tsc[b * gridDim.x + blockIdx.x];
    __syncthreads();
    int per = (E + gridDim.x - 1) / gridDim.x;
    int s = blockIdx.x * per;
    int e = min(E, s + per);
    for (int i = s + threadIdx.x; i < e; i += 256) {
        int d = dst[i];
        int pos = atomicAdd(&cur[d >> 8], 1);
        pairs[pos] = ((unsigned)(d & 255) << 24) | (unsigned)src[i];
    }
}

__global__ __launch_bounds__(256) void bucket_csr_k(
    const unsigned* __restrict__ pairs, const int* __restrict__ Tsc,
    int* __restrict__ row_ptr, float* __restrict__ dis,
    int* __restrict__ csr, int N, int E, int NB, int G)
{
    __shared__ int cnt[256];
    __shared__ int ts[256];
    __shared__ int cur[256];
    const int b = blockIdx.x;
    const int node0 = b << 8;
    const int e0 = Tsc[b * G];
    const int e1 = Tsc[(b + 1) * G];
    const int j = threadIdx.x;
    cnt[j] = 0;
    __syncthreads();
    for (int i = e0 + j; i < e1; i += 256)
        atomicAdd(&cnt[pairs[i] >> 24], 1);
    __syncthreads();
    int c = cnt[j];
    ts[j] = c;
    __syncthreads();
    for (int d = 1; d < 256; d <<= 1) {
        int t = (j >= d) ? ts[j - d] : 0;
        __syncthreads();
        ts[j] += t;
        __syncthreads();
    }
    int excl = ts[j] - c;
    int node = node0 + j;
    if (node < N) {
        row_ptr[node] = e0 + excl;
        dis[node] = rsqrtf(1.0f + (float)c);
    }
    cur[j] = e0 + excl;
    if (b == NB - 1 && j == 0) row_ptr[N] = E;
    __syncthreads();
    for (int i = e0 + j; i < e1; i += 256) {
        unsigned p = pairs[i];
        int pos = atomicAdd(&cur[p >> 24], 1);
        csr[pos] = (int)(p & 0xFFFFFFu);
    }
}

// ---------------- W fragment prebuild: all 3 layers, one kernel ----------------

__device__ inline void wfrag_seg(const float* __restrict__ W,
                                 __hip_bfloat16* __restrict__ out, int idx,
                                 int FIN, int FOUT, int NKK)
{
    int e = idx & 7;
    int lane = (idx >> 3) & 63;
    int t = idx >> 9;
    int kk = t % NKK, nn = t / NKK;
    int col = nn * 16 + (lane & 15);
    int k = kk * 32 + (lane >> 4) * 8 + e;
    float v = (k < FIN && col < FOUT) ? W[k * FOUT + col] : 0.f;
    out[idx] = __float2bfloat16(v);
}

__global__ void wfrag_all_k(const float* __restrict__ W1,
                            const float* __restrict__ W2,
                            const float* __restrict__ W3,
                            __hip_bfloat16* __restrict__ WF)
{
    int idx = blockIdx.x * 256 + threadIdx.x;
    if (idx < 12288)       wfrag_seg(W1, WF,          idx,          128, 84, 4);
    else if (idx < 18432)  wfrag_seg(W2, WF + 12288,  idx - 12288,   84, 64, 3);
    else if (idx < 20480)  wfrag_seg(W3, WF + 18432,  idx - 18432,   64, 32, 2);
}

// ---------------- GEMM v6: MFMA, no LDS; f32 or bf16 input ----------------

template<int FIN>
__device__ inline bf16x8 load_a8f(const float* __restrict__ p, int k0) {
    bf16x8 r;
    if (k0 + 8 <= FIN) {
        float4 v0 = *reinterpret_cast<const float4*>(p + k0);
        float4 v1 = *reinterpret_cast<const float4*>(p + k0 + 4);
        r[0] = f2bf(v0.x); r[1] = f2bf(v0.y); r[2] = f2bf(v0.z); r[3] = f2bf(v0.w);
        r[4] = f2bf(v1.x); r[5] = f2bf(v1.y); r[6] = f2bf(v1.z); r[7] = f2bf(v1.w);
    } else {
#pragma unroll
        for (int e = 0; e < 8; ++e)
            r[e] = (k0 + e < FIN) ? f2bf(p[k0 + e]) : (short)0;
    }
    return r;
}

template<int FIN>
__device__ inline bf16x8 load_a8b(const __hip_bfloat16* __restrict__ p, int k0) {
    if (k0 + 8 <= FIN)
        return *reinterpret_cast<const bf16x8*>(p + k0);
    bf16x8 r;
    const short* ps = (const short*)p;
#pragma unroll
    for (int e = 0; e < 8; ++e)
        r[e] = (k0 + e < FIN) ? ps[k0 + e] : (short)0;
    return r;
}

template<typename TIN, int FIN, int SIN, int FOUT, int HS, int NKK, int CT>
__global__ __launch_bounds__(256) void gemm_mfma_v6(
    const TIN* __restrict__ in, const __hip_bfloat16* __restrict__ wfrag,
    const float* __restrict__ dis, __hip_bfloat16* __restrict__ hh, int n)
{
    const int tid = threadIdx.x;
    const long long base = (long long)blockIdx.x * 64;
    const int cnt = (int)min((long long)64, (long long)n - base);
    const int wv = tid >> 6, lane = tid & 63;
    const int rlo = lane & 15, kg = lane >> 4, kb = kg * 8;
    const int arow = wv * 16 + rlo;
    const long long row = base + arow;

    bf16x8 a[NKK];
    if (arow < cnt) {
        const TIN* p = &in[(size_t)row * SIN];
#pragma unroll
        for (int kk = 0; kk < NKK; ++kk) {
            if constexpr (sizeof(TIN) == 4)
                a[kk] = load_a8f<FIN>((const float*)p, kk * 32 + kb);
            else
                a[kk] = load_a8b<FIN>((const __hip_bfloat16*)p, kk * 32 + kb);
        }
    } else {
#pragma unroll
        for (int kk = 0; kk < NKK; ++kk)
            a[kk] = (bf16x8){0, 0, 0, 0, 0, 0, 0, 0};
    }

    f32x4 acc[CT];
#pragma unroll
    for (int nn = 0; nn < CT; ++nn) acc[nn] = (f32x4){0.f, 0.f, 0.f, 0.f};

#pragma unroll
    for (int nn = 0; nn < CT; ++nn) {
#pragma unroll
        for (int kk = 0; kk < NKK; ++kk) {
            bf16x8 b = *reinterpret_cast<const bf16x8*>(
                &wfrag[(size_t)((nn * NKK + kk) * 64 + lane) * 8]);
            acc[nn] = __builtin_amdgcn_mfma_f32_16x16x32_bf16(a[kk], b, acc[nn], 0, 0, 0);
        }
    }

    const int r0 = wv * 16 + kg * 4;
    float dv[4];
#pragma unroll
    for (int i = 0; i < 4; ++i)
        dv[i] = (r0 + i < cnt) ? dis[base + r0 + i] : 0.f;
#pragma unroll
    for (int nn = 0; nn < CT; ++nn) {
        const int col = nn * 16 + rlo;
        if (col < FOUT) {
#pragma unroll
            for (int i = 0; i < 4; ++i) {
                int r = r0 + i;
                if (r < cnt) {
                    __hip_bfloat16 o = __float2bfloat16(acc[nn][i] * dv[i]);
                    hh[(size_t)(base + r) * HS + col] = o;
                }
            }
        }
    }
}

// ---------------- CSR aggregate v5: 8-deep MLP, strided, bf16/f32 out ----------------

template<int F, int HS, int SO, typename TOUT>
__global__ __launch_bounds__(256) void aggregate_v5(
    const __hip_bfloat16* __restrict__ hh, const int* __restrict__ row_ptr,
    const int* __restrict__ csr, const float* __restrict__ dis,
    const float* __restrict__ b, TOUT* __restrict__ out, int n)
{
    constexpr int FG = F / 4;
    long long idx = (long long)blockIdx.x * 256 + threadIdx.x;
    if (idx >= (long long)n * FG) return;
    int node = (int)(idx / FG);
    int fg = (int)(idx - (long long)node * FG);
    const int bf = fg * 4;

    const unsigned short* hs = (const unsigned short*)hh;
    auto lo16 = [](unsigned u) { return __uint_as_float(u << 16); };
    auto hi16 = [](unsigned u) { return __uint_as_float(u & 0xFFFF0000u); };

    uint2 su = *reinterpret_cast<const uint2*>(&hs[(size_t)node * HS + bf]);
    float a0 = lo16(su.x), a1 = hi16(su.x), a2 = lo16(su.y), a3 = hi16(su.y);
    float c0 = 0.f, c1 = 0.f, c2 = 0.f, c3 = 0.f;

    int e = row_ptr[node];
    const int e1 = row_ptr[node + 1];
    for (; e + 8 <= e1; e += 8) {
        int s0 = csr[e],     s1 = csr[e + 1], s2 = csr[e + 2], s3 = csr[e + 3];
        int s4 = csr[e + 4], s5 = csr[e + 5], s6 = csr[e + 6], s7 = csr[e + 7];
        uint2 u0 = *reinterpret_cast<const uint2*>(&hs[(size_t)s0 * HS + bf]);
        uint2 u1 = *reinterpret_cast<const uint2*>(&hs[(size_t)s1 * HS + bf]);
        uint2 u2 = *reinterpret_cast<const uint2*>(&hs[(size_t)s2 * HS + bf]);
        uint2 u3 = *reinterpret_cast<const uint2*>(&hs[(size_t)s3 * HS + bf]);
        uint2 u4 = *reinterpret_cast<const uint2*>(&hs[(size_t)s4 * HS + bf]);
        uint2 u5 = *reinterpret_cast<const uint2*>(&hs[(size_t)s5 * HS + bf]);
        uint2 u6 = *reinterpret_cast<const uint2*>(&hs[(size_t)s6 * HS + bf]);
        uint2 u7 = *reinterpret_cast<const uint2*>(&hs[(size_t)s7 * HS + bf]);
        a0 += lo16(u0.x); a1 += hi16(u0.x); a2 += lo16(u0.y); a3 += hi16(u0.y);
        c0 += lo16(u1.x); c1 += hi16(u1.x); c2 += lo16(u1.y); c3 += hi16(u1.y);
        a0 += lo16(u2.x); a1 += hi16(u2.x); a2 += lo16(u2.y); a3 += hi16(u2.y);
        c0 += lo16(u3.x); c1 += hi16(u3.x); c2 += lo16(u3.y); c3 += hi16(u3.y);
        a0 += lo16(u4.x); a1 += hi16(u4.x); a2 += lo16(u4.y); a3 += hi16(u4.y);
        c0 += lo16(u5.x); c1 += hi16(u5.x); c2 += lo16(u5.y); c3 += hi16(u5.y);
        a0 += lo16(u6.x); a1 += hi16(u6.x); a2 += lo16(u6.y); a3 += hi16(u6.y);
        c0 += lo16(u7.x); c1 += hi16(u7.x); c2 += lo16(u7.y); c3 += hi16(u7.y);
    }
    if (e + 4 <= e1) {
        int s0 = csr[e], s1 = csr[e + 1], s2 = csr[e + 2], s3 = csr[e + 3];
        uint2 u0 = *reinterpret_cast<const uint2*>(&hs[(size_t)s0 * HS + bf]);
        uint2 u1 = *reinterpret_cast<const uint2*>(&hs[(size_t)s1 * HS + bf]);
        uint2 u2 = *reinterpret_cast<const uint2*>(&hs[(size_t)s2 * HS + bf]);
        uint2 u3 = *reinterpret_cast<const uint2*>(&hs[(size_t)s3 * HS + bf]);
        a0 += lo16(u0.x); a1 += hi16(u0.x); a2 += lo16(u0.y); a3 += hi16(u0.y);
        c0 += lo16(u1.x); c1 += hi16(u1.x); c2 += lo16(u1.y); c3 += hi16(u1.y);
        a0 += lo16(u2.x); a1 += hi16(u2.x); a2 += lo16(u2.y); a3 += hi16(u2.y);
        c0 += lo16(u3.x); c1 += hi16(u3.x); c2 += lo16(u3.y); c3 += hi16(u3.y);
        e += 4;
    }
    for (; e < e1; ++e) {
        int s = csr[e];
        uint2 u = *reinterpret_cast<const uint2*>(&hs[(size_t)s * HS + bf]);
        a0 += lo16(u.x); a1 += hi16(u.x); a2 += lo16(u.y); a3 += hi16(u.y);
    }
    a0 += c0; a1 += c1; a2 += c2; a3 += c3;

    float d = dis[node];
    float4 bb = *reinterpret_cast<const float4*>(&b[bf]);
    float r0 = fmaxf(fmaf(d, a0, bb.x), 0.0f);
    float r1 = fmaxf(fmaf(d, a1, bb.y), 0.0f);
    float r2 = fmaxf(fmaf(d, a2, bb.z), 0.0f);
    float r3 = fmaxf(fmaf(d, a3, bb.w), 0.0f);

    if constexpr (sizeof(TOUT) == 2) {
        alignas(8) __hip_bfloat16 o[4];
        o[0] = __float2bfloat16(r0);
        o[1] = __float2bfloat16(r1);
        o[2] = __float2bfloat16(r2);
        o[3] = __float2bfloat16(r3);
        *reinterpret_cast<uint2*>(&((__hip_bfloat16*)out)[(size_t)node * SO + bf]) =
            *reinterpret_cast<const uint2*>(o);
    } else {
        float4 o;
        o.x = r0; o.y = r1; o.z = r2; o.w = r3;
        *reinterpret_cast<float4*>(&((float*)out)[(size_t)node * SO + bf]) = o;
    }
}

// ---------------- layer-3 aggregate fused with mean-pool (F=32, HS=32) ----------------
// Output rows never materialized: relu'd values go straight into LDS pool sums,
// then one sparse global-atomic flush per block (~2 graphs x 32 feats).

__global__ __launch_bounds__(256) void agg_pool_k(
    const __hip_bfloat16* __restrict__ hh, const int* __restrict__ row_ptr,
    const int* __restrict__ csr, const float* __restrict__ dis,
    const float* __restrict__ b, const int* __restrict__ batch,
    float* __restrict__ sums, float* __restrict__ cnt, int n)
{
    __shared__ float s[64 * 32];
    __shared__ float sc[64];
    for (int i = threadIdx.x; i < 64 * 32; i += 256) s[i] = 0.0f;
    if (threadIdx.x < 64) sc[threadIdx.x] = 0.0f;
    __syncthreads();

    constexpr int HS = 32;
    long long idx = (long long)blockIdx.x * 256 + threadIdx.x;
    if (idx < (long long)n * 8) {
        int node = (int)(idx >> 3);
        int fg = (int)(idx & 7);
        const int bf = fg * 4;

        const unsigned short* hs = (const unsigned short*)hh;
        auto lo16 = [](unsigned u) { return __uint_as_float(u << 16); };
        auto hi16 = [](unsigned u) { return __uint_as_float(u & 0xFFFF0000u); };

        uint2 su = *reinterpret_cast<const uint2*>(&hs[(size_t)node * HS + bf]);
        float a0 = lo16(su.x), a1 = hi16(su.x), a2 = lo16(su.y), a3 = hi16(su.y);
        float c0 = 0.f, c1 = 0.f, c2 = 0.f, c3 = 0.f;

        int e = row_ptr[node];
        const int e1 = row_ptr[node + 1];
        for (; e + 8 <= e1; e += 8) {
            int s0 = csr[e],     s1 = csr[e + 1], s2 = csr[e + 2], s3 = csr[e + 3];
            int s4 = csr[e + 4], s5 = csr[e + 5], s6 = csr[e + 6], s7 = csr[e + 7];
            uint2 u0 = *reinterpret_cast<const uint2*>(&hs[(size_t)s0 * HS + bf]);
            uint2 u1 = *reinterpret_cast<const uint2*>(&hs[(size_t)s1 * HS + bf]);
            uint2 u2 = *reinterpret_cast<const uint2*>(&hs[(size_t)s2 * HS + bf]);
            uint2 u3 = *reinterpret_cast<const uint2*>(&hs[(size_t)s3 * HS + bf]);
            uint2 u4 = *reinterpret_cast<const uint2*>(&hs[(size_t)s4 * HS + bf]);
            uint2 u5 = *reinterpret_cast<const uint2*>(&hs[(size_t)s5 * HS + bf]);
            uint2 u6 = *reinterpret_cast<const uint2*>(&hs[(size_t)s6 * HS + bf]);
            uint2 u7 = *reinterpret_cast<const uint2*>(&hs[(size_t)s7 * HS + bf]);
            a0 += lo16(u0.x); a1 += hi16(u0.x); a2 += lo16(u0.y); a3 += hi16(u0.y);
            c0 += lo16(u1.x); c1 += hi16(u1.x); c2 += lo16(u1.y); c3 += hi16(u1.y);
            a0 += lo16(u2.x); a1 += hi16(u2.x); a2 += lo16(u2.y); a3 += hi16(u2.y);
            c0 += lo16(u3.x); c1 += hi16(u3.x); c2 += lo16(u3.y); c3 += hi16(u3.y);
            a0 += lo16(u4.x); a1 += hi16(u4.x); a2 += lo16(u4.y); a3 += hi16(u4.y);
            c0 += lo16(u5.x); c1 += hi16(u5.x); c2 += lo16(u5.y); c3 += hi16(u5.y);
            a0 += lo16(u6.x); a1 += hi16(u6.x); a2 += lo16(u6.y); a3 += hi16(u6.y);
            c0 += lo16(u7.x); c1 += hi16(u7.x); c2 += lo16(u7.y); c3 += hi16(u7.y);
        }
        if (e + 4 <= e1) {
            int s0 = csr[e], s1 = csr[e + 1], s2 = csr[e + 2], s3 = csr[e + 3];
            uint2 u0 = *reinterpret_cast<const uint2*>(&hs[(size_t)s0 * HS + bf]);
            uint2 u1 = *reinterpret_cast<const uint2*>(&hs[(size_t)s1 * HS + bf]);
            uint2 u2 = *reinterpret_cast<const uint2*>(&hs[(size_t)s2 * HS + bf]);
            uint2 u3 = *reinterpret_cast<const uint2*>(&hs[(size_t)s3 * HS + bf]);
            a0 += lo16(u0.x); a1 += hi16(u0.x); a2 += lo16(u0.y); a3 += hi16(u0.y);
            c0 += lo16(u1.x); c1 += hi16(u1.x); c2 += lo16(u1.y); c3 += hi16(u1.y);
            a0 += lo16(u2.x); a1 += hi16(u2.x); a2 += lo16(u2.y); a3 += hi16(u2.y);
            c0 += lo16(u3.x); c1 += hi16(u3.x); c2 += lo16(u3.y); c3 += hi16(u3.y);
            e += 4;
        }
        for (; e < e1; ++e) {
            int sx = csr[e];
            uint2 u = *reinterpret_cast<const uint2*>(&hs[(size_t)sx * HS + bf]);
            a0 += lo16(u.x); a1 += hi16(u.x); a2 += lo16(u.y); a3 += hi16(u.y);
        }
        a0 += c0; a1 += c1; a2 += c2; a3 += c3;

        float d = dis[node];
        float4 bb = *reinterpret_cast<const float4*>(&b[bf]);
        float r0 = fmaxf(fmaf(d, a0, bb.x), 0.0f);
        float r1 = fmaxf(fmaf(d, a1, bb.y), 0.0f);
        float r2 = fmaxf(fmaf(d, a2, bb.z), 0.0f);
        float r3 = fmaxf(fmaf(d, a3, bb.w), 0.0f);

        int g = batch[node];
        atomicAdd(&s[g * 32 + bf + 0], r0);
        atomicAdd(&s[g * 32 + bf + 1], r1);
        atomicAdd(&s[g * 32 + bf + 2], r2);
        atomicAdd(&s[g * 32 + bf + 3], r3);
        if (fg == 0) atomicAdd(&sc[g], 1.0f);
    }
    __syncthreads();
    for (int i = threadIdx.x; i < 64 * 32; i += 256) {
        float v = s[i];
        if (v != 0.0f) atomicAdd(&sums[i], v);
    }
    if (threadIdx.x < 64) {
        float v = sc[threadIdx.x];
        if (v != 0.0f) atomicAdd(&cnt[threadIdx.x], v);
    }
}

__global__ void head_k(const float* __restrict__ sums, const float* __restrict__ cnt,
                       const float* __restrict__ Wl, const float* __restrict__ bl,
                       float* __restrict__ out)
{
    int tid = threadIdx.x;
    if (tid < 128) {
        int g = tid >> 1;
        int o = tid & 1;
        float c = fmaxf(cnt[g], 1.0f);
        float a = 0.0f;
#pragma unroll
        for (int f = 0; f < 32; ++f)
            a += (sums[g * 32 + f] / c) * Wl[f * 2 + o];
        out[tid] = a + bl[o];
    }
}

// ---------------- launch ----------------

extern "C" void kernel_launch(void* const* d_in, const int* in_sizes, int n_in,
                              void* d_out, int out_size, void* d_ws, size_t ws_size,
                              hipStream_t stream)
{
    const float* x   = (const float*)d_in[0];
    const int*   ei  = (const int*)d_in[1];
    const int*   bat = (const int*)d_in[2];
    const float* W1  = (const float*)d_in[3];
    const float* b1  = (const float*)d_in[4];
    const float* W2  = (const float*)d_in[5];
    const float* b2  = (const float*)d_in[6];
    const float* W3  = (const float*)d_in[7];
    const float* b3  = (const float*)d_in[8];
    const float* Wl  = (const float*)d_in[9];
    const float* bl  = (const float*)d_in[10];

    const int N = in_sizes[0] / 128;
    const int E = in_sizes[1] / 2;
    const int* src = ei;
    const int* dst = ei + E;

    const int NB = (N + 255) >> 8;
    const int G  = 128;
    const int NBG = NB * G;

    char* ws = (char*)d_ws;
    size_t off = 0;
    auto alloc = [&](size_t bytes) -> char* {
        char* p = ws + off;
        off += (bytes + 255) & ~(size_t)255;
        return p;
    };
    float* dis     = (float*)alloc((size_t)N * 4);
    int*   row_ptr = (int*)  alloc((size_t)(N + 1) * 4);
    int*   bsum    = (int*)  alloc(256 * 4);
    int*   csr     = (int*)  alloc((size_t)E * 4);
    int*   T       = (int*)  alloc((size_t)NBG * 4);
    int*   Tsc     = (int*)  alloc((size_t)(NBG + 1) * 4);
    __hip_bfloat16* WF = (__hip_bfloat16*)alloc(20480 * 2);  // WF1|WF2|WF3
    __hip_bfloat16* A = (__hip_bfloat16*)alloc((size_t)N * 96 * 2);
    __hip_bfloat16* B = (__hip_bfloat16*)alloc((size_t)N * 96 * 2);
    __hip_bfloat16* C = (__hip_bfloat16*)alloc((size_t)N * 64 * 2);
    float* D       = (float*)alloc((size_t)(64 * 32 + 64) * 4);
    unsigned* pairs = (unsigned*)C;  // overlay, prologue only
    __hip_bfloat16* WF2 = WF + 12288;
    __hip_bfloat16* WF3 = WF + 18432;

    dim3 blk(256);
    auto cdiv = [](long long a, long long b) { return (int)((a + b - 1) / b); };

    // pool accumulators zeroed via async memset (graph-capturable)
    hipMemsetAsync(D, 0, (64 * 32 + 64) * 4, stream);

    // ---- W fragment prebuild (single kernel) ----
    wfrag_all_k<<<cdiv(20480, 256), blk, 0, stream>>>(W1, W2, W3, WF);

    // ---- bucketed CSR build ----
    bucket_hist_k<<<G, blk, 0, stream>>>(dst, T, E, NB);
    int nb_scan = cdiv(NBG, 2048);
    scan_block_k<<<nb_scan, blk, 0, stream>>>(T, Tsc, bsum, NBG);
    scan_partials_k<<<1, 64, 0, stream>>>(bsum, nb_scan);
    scan_add_k<<<cdiv(NBG, 256), blk, 0, stream>>>(Tsc, bsum, NBG, E);
    bucket_scatter_k<<<G, blk, 0, stream>>>(src, dst, Tsc, pairs, E, NB);
    bucket_csr_k<<<NB, blk, 0, stream>>>(pairs, Tsc, row_ptr, dis, csr, N, E, NB, G);

    // Layer 1: 128 -> 84 (hh stride 96; out B bf16 stride 96)
    gemm_mfma_v6<float, 128, 128, 84, 96, 4, 6><<<cdiv(N, 64), blk, 0, stream>>>(x, WF, dis, A, N);
    aggregate_v5<84, 96, 96, __hip_bfloat16><<<cdiv((long long)N * 21, 256), blk, 0, stream>>>(
        A, row_ptr, csr, dis, b1, B, N);

    // Layer 2: 84 -> 64 (in B bf16 stride 96; hh stride 64; out C bf16 stride 64)
    gemm_mfma_v6<__hip_bfloat16, 84, 96, 64, 64, 3, 4><<<cdiv(N, 64), blk, 0, stream>>>(B, WF2, dis, A, N);
    aggregate_v5<64, 64, 64, __hip_bfloat16><<<cdiv((long long)N * 16, 256), blk, 0, stream>>>(
        A, row_ptr, csr, dis, b2, C, N);

    // Layer 3: 64 -> 32, aggregate fused with mean-pool (no materialized output)
    gemm_mfma_v6<__hip_bfloat16, 64, 64, 32, 32, 2, 2><<<cdiv(N, 64), blk, 0, stream>>>(C, WF3, dis, A, N);
    agg_pool_k<<<cdiv((long long)N * 8, 256), blk, 0, stream>>>(
        A, row_ptr, csr, dis, b3, bat, D, D + 64 * 32, N);

    // head
    head_k<<<1, 128, 0, stream>>>(D, D + 64 * 32, Wl, bl, (float*)d_out);
}

// Round 18
// 256.002 us; speedup vs baseline: 1.2055x; 1.0467x over previous
//
#include <hip/hip_runtime.h>
#include <hip/hip_bf16.h>

typedef __attribute__((ext_vector_type(8))) short bf16x8;
typedef __attribute__((ext_vector_type(4))) float f32x4;

__device__ inline short f2bf(float f) {
    __hip_bfloat16 h = __float2bfloat16(f);
    return *reinterpret_cast<short*>(&h);
}

// ---------------- bucketed CSR build (no global atomics) ----------------
// pairs packed: (dst&255)<<24 | src   (src < 2^24)

__global__ __launch_bounds__(256) void bucket_hist_k(
    const int* __restrict__ dst, int* __restrict__ T, int E, int NB)
{
    __shared__ int hist[512];
    for (int b = threadIdx.x; b < NB; b += 256) hist[b] = 0;
    __syncthreads();
    int per = (E + gridDim.x - 1) / gridDim.x;
    int s = blockIdx.x * per;
    int e = min(E, s + per);
    for (int i = s + threadIdx.x; i < e; i += 256)
        atomicAdd(&hist[dst[i] >> 8], 1);
    __syncthreads();
    for (int b = threadIdx.x; b < NB; b += 256)
        T[b * gridDim.x + blockIdx.x] = hist[b];
}

__global__ __launch_bounds__(256) void scan_block_k(
    const int* __restrict__ in, int* __restrict__ out,
    int* __restrict__ bsum, int n)
{
    __shared__ int ts[256];
    int base = blockIdx.x * 2048;
    int i0 = base + threadIdx.x * 8;
    int vals[8];
    int s = 0;
#pragma unroll
    for (int j = 0; j < 8; ++j) {
        int v = (i0 + j) < n ? in[i0 + j] : 0;
        vals[j] = v; s += v;
    }
    ts[threadIdx.x] = s;
    __syncthreads();
    for (int d = 1; d < 256; d <<= 1) {
        int t = (threadIdx.x >= (unsigned)d) ? ts[threadIdx.x - d] : 0;
        __syncthreads();
        ts[threadIdx.x] += t;
        __syncthreads();
    }
    int run = ts[threadIdx.x] - s;
    if (threadIdx.x == 255) bsum[blockIdx.x] = ts[255];
#pragma unroll
    for (int j = 0; j < 8; ++j) {
        if (i0 + j < n) out[i0 + j] = run;
        run += vals[j];
    }
}

__global__ void scan_partials_k(int* __restrict__ bsum, int nb) {
    if (threadIdx.x == 0 && blockIdx.x == 0) {
        int run = 0;
        for (int i = 0; i < nb; ++i) { int t = bsum[i]; bsum[i] = run; run += t; }
    }
}

__global__ void scan_add_k(int* __restrict__ rp, const int* __restrict__ bsum,
                           int n, int E)
{
    int i = blockIdx.x * blockDim.x + threadIdx.x;
    if (i < n) rp[i] += bsum[i >> 11];
    if (i == 0) rp[n] = E;
}

__global__ __launch_bounds__(256) void bucket_scatter_k(
    const int* __restrict__ src, const int* __restrict__ dst,
    const int* __restrict__ Tsc, unsigned* __restrict__ pairs, int E, int NB)
{
    __shared__ int cur[512];
    for (int b = threadIdx.x; b < NB; b += 256)
        cur[b] = Tsc[b * gridDim.x + blockIdx.x];
    __syncthreads();
    int per = (E + gridDim.x - 1) / gridDim.x;
    int s = blockIdx.x * per;
    int e = min(E, s + per);
    for (int i = s + threadIdx.x; i < e; i += 256) {
        int d = dst[i];
        int pos = atomicAdd(&cur[d >> 8], 1);
        pairs[pos] = ((unsigned)(d & 255) << 24) | (unsigned)src[i];
    }
}

__global__ __launch_bounds__(256) void bucket_csr_k(
    const unsigned* __restrict__ pairs, const int* __restrict__ Tsc,
    int* __restrict__ row_ptr, float* __restrict__ dis,
    int* __restrict__ csr, int N, int E, int NB, int G)
{
    __shared__ int cnt[256];
    __shared__ int ts[256];
    __shared__ int cur[256];
    const int b = blockIdx.x;
    const int node0 = b << 8;
    const int e0 = Tsc[b * G];
    const int e1 = Tsc[(b + 1) * G];
    const int j = threadIdx.x;
    cnt[j] = 0;
    __syncthreads();
    for (int i = e0 + j; i < e1; i += 256)
        atomicAdd(&cnt[pairs[i] >> 24], 1);
    __syncthreads();
    int c = cnt[j];
    ts[j] = c;
    __syncthreads();
    for (int d = 1; d < 256; d <<= 1) {
        int t = (j >= d) ? ts[j - d] : 0;
        __syncthreads();
        ts[j] += t;
        __syncthreads();
    }
    int excl = ts[j] - c;
    int node = node0 + j;
    if (node < N) {
        row_ptr[node] = e0 + excl;
        dis[node] = rsqrtf(1.0f + (float)c);
    }
    cur[j] = e0 + excl;
    if (b == NB - 1 && j == 0) row_ptr[N] = E;
    __syncthreads();
    for (int i = e0 + j; i < e1; i += 256) {
        unsigned p = pairs[i];
        int pos = atomicAdd(&cur[p >> 24], 1);
        csr[pos] = (int)(p & 0xFFFFFFu);
    }
}

// ---------------- W fragment prebuild: all 3 layers, one kernel ----------------

__device__ inline void wfrag_seg(const float* __restrict__ W,
                                 __hip_bfloat16* __restrict__ out, int idx,
                                 int FIN, int FOUT, int NKK)
{
    int e = idx & 7;
    int lane = (idx >> 3) & 63;
    int t = idx >> 9;
    int kk = t % NKK, nn = t / NKK;
    int col = nn * 16 + (lane & 15);
    int k = kk * 32 + (lane >> 4) * 8 + e;
    float v = (k < FIN && col < FOUT) ? W[k * FOUT + col] : 0.f;
    out[idx] = __float2bfloat16(v);
}

__global__ void wfrag_all_k(const float* __restrict__ W1,
                            const float* __restrict__ W2,
                            const float* __restrict__ W3,
                            __hip_bfloat16* __restrict__ WF)
{
    int idx = blockIdx.x * 256 + threadIdx.x;
    if (idx < 12288)       wfrag_seg(W1, WF,          idx,          128, 84, 4);
    else if (idx < 18432)  wfrag_seg(W2, WF + 12288,  idx - 12288,   84, 64, 3);
    else if (idx < 20480)  wfrag_seg(W3, WF + 18432,  idx - 18432,   64, 32, 2);
}

// ---------------- GEMM v6: MFMA, no LDS; f32 or bf16 input ----------------

template<int FIN>
__device__ inline bf16x8 load_a8f(const float* __restrict__ p, int k0) {
    bf16x8 r;
    if (k0 + 8 <= FIN) {
        float4 v0 = *reinterpret_cast<const float4*>(p + k0);
        float4 v1 = *reinterpret_cast<const float4*>(p + k0 + 4);
        r[0] = f2bf(v0.x); r[1] = f2bf(v0.y); r[2] = f2bf(v0.z); r[3] = f2bf(v0.w);
        r[4] = f2bf(v1.x); r[5] = f2bf(v1.y); r[6] = f2bf(v1.z); r[7] = f2bf(v1.w);
    } else {
#pragma unroll
        for (int e = 0; e < 8; ++e)
            r[e] = (k0 + e < FIN) ? f2bf(p[k0 + e]) : (short)0;
    }
    return r;
}

template<int FIN>
__device__ inline bf16x8 load_a8b(const __hip_bfloat16* __restrict__ p, int k0) {
    if (k0 + 8 <= FIN)
        return *reinterpret_cast<const bf16x8*>(p + k0);
    bf16x8 r;
    const short* ps = (const short*)p;
#pragma unroll
    for (int e = 0; e < 8; ++e)
        r[e] = (k0 + e < FIN) ? ps[k0 + e] : (short)0;
    return r;
}

template<typename TIN, int FIN, int SIN, int FOUT, int HS, int NKK, int CT>
__global__ __launch_bounds__(256) void gemm_mfma_v6(
    const TIN* __restrict__ in, const __hip_bfloat16* __restrict__ wfrag,
    const float* __restrict__ dis, __hip_bfloat16* __restrict__ hh, int n)
{
    const int tid = threadIdx.x;
    const long long base = (long long)blockIdx.x * 64;
    const int cnt = (int)min((long long)64, (long long)n - base);
    const int wv = tid >> 6, lane = tid & 63;
    const int rlo = lane & 15, kg = lane >> 4, kb = kg * 8;
    const int arow = wv * 16 + rlo;
    const long long row = base + arow;

    bf16x8 a[NKK];
    if (arow < cnt) {
        const TIN* p = &in[(size_t)row * SIN];
#pragma unroll
        for (int kk = 0; kk < NKK; ++kk) {
            if constexpr (sizeof(TIN) == 4)
                a[kk] = load_a8f<FIN>((const float*)p, kk * 32 + kb);
            else
                a[kk] = load_a8b<FIN>((const __hip_bfloat16*)p, kk * 32 + kb);
        }
    } else {
#pragma unroll
        for (int kk = 0; kk < NKK; ++kk)
            a[kk] = (bf16x8){0, 0, 0, 0, 0, 0, 0, 0};
    }

    f32x4 acc[CT];
#pragma unroll
    for (int nn = 0; nn < CT; ++nn) acc[nn] = (f32x4){0.f, 0.f, 0.f, 0.f};

#pragma unroll
    for (int nn = 0; nn < CT; ++nn) {
#pragma unroll
        for (int kk = 0; kk < NKK; ++kk) {
            bf16x8 b = *reinterpret_cast<const bf16x8*>(
                &wfrag[(size_t)((nn * NKK + kk) * 64 + lane) * 8]);
            acc[nn] = __builtin_amdgcn_mfma_f32_16x16x32_bf16(a[kk], b, acc[nn], 0, 0, 0);
        }
    }

    const int r0 = wv * 16 + kg * 4;
    float dv[4];
#pragma unroll
    for (int i = 0; i < 4; ++i)
        dv[i] = (r0 + i < cnt) ? dis[base + r0 + i] : 0.f;
#pragma unroll
    for (int nn = 0; nn < CT; ++nn) {
        const int col = nn * 16 + rlo;
        if (col < FOUT) {
#pragma unroll
            for (int i = 0; i < 4; ++i) {
                int r = r0 + i;
                if (r < cnt) {
                    __hip_bfloat16 o = __float2bfloat16(acc[nn][i] * dv[i]);
                    hh[(size_t)(base + r) * HS + col] = o;
                }
            }
        }
    }
}

// ---------------- CSR aggregate v5: 8-deep MLP, strided, bf16/f32 out ----------------

template<int F, int HS, int SO, typename TOUT>
__global__ __launch_bounds__(256) void aggregate_v5(
    const __hip_bfloat16* __restrict__ hh, const int* __restrict__ row_ptr,
    const int* __restrict__ csr, const float* __restrict__ dis,
    const float* __restrict__ b, TOUT* __restrict__ out, int n)
{
    constexpr int FG = F / 4;
    long long idx = (long long)blockIdx.x * 256 + threadIdx.x;
    if (idx >= (long long)n * FG) return;
    int node = (int)(idx / FG);
    int fg = (int)(idx - (long long)node * FG);
    const int bf = fg * 4;

    const unsigned short* hs = (const unsigned short*)hh;
    auto lo16 = [](unsigned u) { return __uint_as_float(u << 16); };
    auto hi16 = [](unsigned u) { return __uint_as_float(u & 0xFFFF0000u); };

    uint2 su = *reinterpret_cast<const uint2*>(&hs[(size_t)node * HS + bf]);
    float a0 = lo16(su.x), a1 = hi16(su.x), a2 = lo16(su.y), a3 = hi16(su.y);
    float c0 = 0.f, c1 = 0.f, c2 = 0.f, c3 = 0.f;

    int e = row_ptr[node];
    const int e1 = row_ptr[node + 1];
    for (; e + 8 <= e1; e += 8) {
        int s0 = csr[e],     s1 = csr[e + 1], s2 = csr[e + 2], s3 = csr[e + 3];
        int s4 = csr[e + 4], s5 = csr[e + 5], s6 = csr[e + 6], s7 = csr[e + 7];
        uint2 u0 = *reinterpret_cast<const uint2*>(&hs[(size_t)s0 * HS + bf]);
        uint2 u1 = *reinterpret_cast<const uint2*>(&hs[(size_t)s1 * HS + bf]);
        uint2 u2 = *reinterpret_cast<const uint2*>(&hs[(size_t)s2 * HS + bf]);
        uint2 u3 = *reinterpret_cast<const uint2*>(&hs[(size_t)s3 * HS + bf]);
        uint2 u4 = *reinterpret_cast<const uint2*>(&hs[(size_t)s4 * HS + bf]);
        uint2 u5 = *reinterpret_cast<const uint2*>(&hs[(size_t)s5 * HS + bf]);
        uint2 u6 = *reinterpret_cast<const uint2*>(&hs[(size_t)s6 * HS + bf]);
        uint2 u7 = *reinterpret_cast<const uint2*>(&hs[(size_t)s7 * HS + bf]);
        a0 += lo16(u0.x); a1 += hi16(u0.x); a2 += lo16(u0.y); a3 += hi16(u0.y);
        c0 += lo16(u1.x); c1 += hi16(u1.x); c2 += lo16(u1.y); c3 += hi16(u1.y);
        a0 += lo16(u2.x); a1 += hi16(u2.x); a2 += lo16(u2.y); a3 += hi16(u2.y);
        c0 += lo16(u3.x); c1 += hi16(u3.x); c2 += lo16(u3.y); c3 += hi16(u3.y);
        a0 += lo16(u4.x); a1 += hi16(u4.x); a2 += lo16(u4.y); a3 += hi16(u4.y);
        c0 += lo16(u5.x); c1 += hi16(u5.x); c2 += lo16(u5.y); c3 += hi16(u5.y);
        a0 += lo16(u6.x); a1 += hi16(u6.x); a2 += lo16(u6.y); a3 += hi16(u6.y);
        c0 += lo16(u7.x); c1 += hi16(u7.x); c2 += lo16(u7.y); c3 += hi16(u7.y);
    }
    if (e + 4 <= e1) {
        int s0 = csr[e], s1 = csr[e + 1], s2 = csr[e + 2], s3 = csr[e + 3];
        uint2 u0 = *reinterpret_cast<const uint2*>(&hs[(size_t)s0 * HS + bf]);
        uint2 u1 = *reinterpret_cast<const uint2*>(&hs[(size_t)s1 * HS + bf]);
        uint2 u2 = *reinterpret_cast<const uint2*>(&hs[(size_t)s2 * HS + bf]);
        uint2 u3 = *reinterpret_cast<const uint2*>(&hs[(size_t)s3 * HS + bf]);
        a0 += lo16(u0.x); a1 += hi16(u0.x); a2 += lo16(u0.y); a3 += hi16(u0.y);
        c0 += lo16(u1.x); c1 += hi16(u1.x); c2 += lo16(u1.y); c3 += hi16(u1.y);
        a0 += lo16(u2.x); a1 += hi16(u2.x); a2 += lo16(u2.y); a3 += hi16(u2.y);
        c0 += lo16(u3.x); c1 += hi16(u3.x); c2 += lo16(u3.y); c3 += hi16(u3.y);
        e += 4;
    }
    for (; e < e1; ++e) {
        int s = csr[e];
        uint2 u = *reinterpret_cast<const uint2*>(&hs[(size_t)s * HS + bf]);
        a0 += lo16(u.x); a1 += hi16(u.x); a2 += lo16(u.y); a3 += hi16(u.y);
    }
    a0 += c0; a1 += c1; a2 += c2; a3 += c3;

    float d = dis[node];
    float4 bb = *reinterpret_cast<const float4*>(&b[bf]);
    float r0 = fmaxf(fmaf(d, a0, bb.x), 0.0f);
    float r1 = fmaxf(fmaf(d, a1, bb.y), 0.0f);
    float r2 = fmaxf(fmaf(d, a2, bb.z), 0.0f);
    float r3 = fmaxf(fmaf(d, a3, bb.w), 0.0f);

    if constexpr (sizeof(TOUT) == 2) {
        alignas(8) __hip_bfloat16 o[4];
        o[0] = __float2bfloat16(r0);
        o[1] = __float2bfloat16(r1);
        o[2] = __float2bfloat16(r2);
        o[3] = __float2bfloat16(r3);
        *reinterpret_cast<uint2*>(&((__hip_bfloat16*)out)[(size_t)node * SO + bf]) =
            *reinterpret_cast<const uint2*>(o);
    } else {
        float4 o;
        o.x = r0; o.y = r1; o.z = r2; o.w = r3;
        *reinterpret_cast<float4*>(&((float*)out)[(size_t)node * SO + bf]) = o;
    }
}

// ---------------- layer-3 aggregate fused with mean-pool (F=32, HS=32) ----------------

__global__ __launch_bounds__(256) void agg_pool_k(
    const __hip_bfloat16* __restrict__ hh, const int* __restrict__ row_ptr,
    const int* __restrict__ csr, const float* __restrict__ dis,
    const float* __restrict__ b, const int* __restrict__ batch,
    float* __restrict__ sums, float* __restrict__ cnt, int n)
{
    __shared__ float s[64 * 32];
    __shared__ float sc[64];
    for (int i = threadIdx.x; i < 64 * 32; i += 256) s[i] = 0.0f;
    if (threadIdx.x < 64) sc[threadIdx.x] = 0.0f;
    __syncthreads();

    constexpr int HS = 32;
    long long idx = (long long)blockIdx.x * 256 + threadIdx.x;
    if (idx < (long long)n * 8) {
        int node = (int)(idx >> 3);
        int fg = (int)(idx & 7);
        const int bf = fg * 4;

        const unsigned short* hs = (const unsigned short*)hh;
        auto lo16 = [](unsigned u) { return __uint_as_float(u << 16); };
        auto hi16 = [](unsigned u) { return __uint_as_float(u & 0xFFFF0000u); };

        uint2 su = *reinterpret_cast<const uint2*>(&hs[(size_t)node * HS + bf]);
        float a0 = lo16(su.x), a1 = hi16(su.x), a2 = lo16(su.y), a3 = hi16(su.y);
        float c0 = 0.f, c1 = 0.f, c2 = 0.f, c3 = 0.f;

        int e = row_ptr[node];
        const int e1 = row_ptr[node + 1];
        for (; e + 8 <= e1; e += 8) {
            int s0 = csr[e],     s1 = csr[e + 1], s2 = csr[e + 2], s3 = csr[e + 3];
            int s4 = csr[e + 4], s5 = csr[e + 5], s6 = csr[e + 6], s7 = csr[e + 7];
            uint2 u0 = *reinterpret_cast<const uint2*>(&hs[(size_t)s0 * HS + bf]);
            uint2 u1 = *reinterpret_cast<const uint2*>(&hs[(size_t)s1 * HS + bf]);
            uint2 u2 = *reinterpret_cast<const uint2*>(&hs[(size_t)s2 * HS + bf]);
            uint2 u3 = *reinterpret_cast<const uint2*>(&hs[(size_t)s3 * HS + bf]);
            uint2 u4 = *reinterpret_cast<const uint2*>(&hs[(size_t)s4 * HS + bf]);
            uint2 u5 = *reinterpret_cast<const uint2*>(&hs[(size_t)s5 * HS + bf]);
            uint2 u6 = *reinterpret_cast<const uint2*>(&hs[(size_t)s6 * HS + bf]);
            uint2 u7 = *reinterpret_cast<const uint2*>(&hs[(size_t)s7 * HS + bf]);
            a0 += lo16(u0.x); a1 += hi16(u0.x); a2 += lo16(u0.y); a3 += hi16(u0.y);
            c0 += lo16(u1.x); c1 += hi16(u1.x); c2 += lo16(u1.y); c3 += hi16(u1.y);
            a0 += lo16(u2.x); a1 += hi16(u2.x); a2 += lo16(u2.y); a3 += hi16(u2.y);
            c0 += lo16(u3.x); c1 += hi16(u3.x); c2 += lo16(u3.y); c3 += hi16(u3.y);
            a0 += lo16(u4.x); a1 += hi16(u4.x); a2 += lo16(u4.y); a3 += hi16(u4.y);
            c0 += lo16(u5.x); c1 += hi16(u5.x); c2 += lo16(u5.y); c3 += hi16(u5.y);
            a0 += lo16(u6.x); a1 += hi16(u6.x); a2 += lo16(u6.y); a3 += hi16(u6.y);
            c0 += lo16(u7.x); c1 += hi16(u7.x); c2 += lo16(u7.y); c3 += hi16(u7.y);
        }
        if (e + 4 <= e1) {
            int s0 = csr[e], s1 = csr[e + 1], s2 = csr[e + 2], s3 = csr[e + 3];
            uint2 u0 = *reinterpret_cast<const uint2*>(&hs[(size_t)s0 * HS + bf]);
            uint2 u1 = *reinterpret_cast<const uint2*>(&hs[(size_t)s1 * HS + bf]);
            uint2 u2 = *reinterpret_cast<const uint2*>(&hs[(size_t)s2 * HS + bf]);
            uint2 u3 = *reinterpret_cast<const uint2*>(&hs[(size_t)s3 * HS + bf]);
            a0 += lo16(u0.x); a1 += hi16(u0.x); a2 += lo16(u0.y); a3 += hi16(u0.y);
            c0 += lo16(u1.x); c1 += hi16(u1.x); c2 += lo16(u1.y); c3 += hi16(u1.y);
            a0 += lo16(u2.x); a1 += hi16(u2.x); a2 += lo16(u2.y); a3 += hi16(u2.y);
            c0 += lo16(u3.x); c1 += hi16(u3.x); c2 += lo16(u3.y); c3 += hi16(u3.y);
            e += 4;
        }
        for (; e < e1; ++e) {
            int sx = csr[e];
            uint2 u = *reinterpret_cast<const uint2*>(&hs[(size_t)sx * HS + bf]);
            a0 += lo16(u.x); a1 += hi16(u.x); a2 += lo16(u.y); a3 += hi16(u.y);
        }
        a0 += c0; a1 += c1; a2 += c2; a3 += c3;

        float d = dis[node];
        float4 bb = *reinterpret_cast<const float4*>(&b[bf]);
        float r0 = fmaxf(fmaf(d, a0, bb.x), 0.0f);
        float r1 = fmaxf(fmaf(d, a1, bb.y), 0.0f);
        float r2 = fmaxf(fmaf(d, a2, bb.z), 0.0f);
        float r3 = fmaxf(fmaf(d, a3, bb.w), 0.0f);

        int g = batch[node];
        atomicAdd(&s[g * 32 + bf + 0], r0);
        atomicAdd(&s[g * 32 + bf + 1], r1);
        atomicAdd(&s[g * 32 + bf + 2], r2);
        atomicAdd(&s[g * 32 + bf + 3], r3);
        if (fg == 0) atomicAdd(&sc[g], 1.0f);
    }
    __syncthreads();
    for (int i = threadIdx.x; i < 64 * 32; i += 256) {
        float v = s[i];
        if (v != 0.0f) atomicAdd(&sums[i], v);
    }
    if (threadIdx.x < 64) {
        float v = sc[threadIdx.x];
        if (v != 0.0f) atomicAdd(&cnt[threadIdx.x], v);
    }
}

__global__ void head_k(const float* __restrict__ sums, const float* __restrict__ cnt,
                       const float* __restrict__ Wl, const float* __restrict__ bl,
                       float* __restrict__ out)
{
    int tid = threadIdx.x;
    if (tid < 128) {
        int g = tid >> 1;
        int o = tid & 1;
        float c = fmaxf(cnt[g], 1.0f);
        float a = 0.0f;
#pragma unroll
        for (int f = 0; f < 32; ++f)
            a += (sums[g * 32 + f] / c) * Wl[f * 2 + o];
        out[tid] = a + bl[o];
    }
}

// ---------------- launch ----------------

extern "C" void kernel_launch(void* const* d_in, const int* in_sizes, int n_in,
                              void* d_out, int out_size, void* d_ws, size_t ws_size,
                              hipStream_t stream)
{
    const float* x   = (const float*)d_in[0];
    const int*   ei  = (const int*)d_in[1];
    const int*   bat = (const int*)d_in[2];
    const float* W1  = (const float*)d_in[3];
    const float* b1  = (const float*)d_in[4];
    const float* W2  = (const float*)d_in[5];
    const float* b2  = (const float*)d_in[6];
    const float* W3  = (const float*)d_in[7];
    const float* b3  = (const float*)d_in[8];
    const float* Wl  = (const float*)d_in[9];
    const float* bl  = (const float*)d_in[10];

    const int N = in_sizes[0] / 128;
    const int E = in_sizes[1] / 2;
    const int* src = ei;
    const int* dst = ei + E;

    const int NB = (N + 255) >> 8;
    const int G  = 256;              // hist/scatter blocks (all CUs busy)
    const int NBG = NB * G;

    char* ws = (char*)d_ws;
    size_t off = 0;
    auto alloc = [&](size_t bytes) -> char* {
        char* p = ws + off;
        off += (bytes + 255) & ~(size_t)255;
        return p;
    };
    float* dis     = (float*)alloc((size_t)N * 4);
    int*   row_ptr = (int*)  alloc((size_t)(N + 1) * 4);
    int*   bsum    = (int*)  alloc(256 * 4);
    int*   csr     = (int*)  alloc((size_t)E * 4);
    int*   T       = (int*)  alloc((size_t)NBG * 4);
    int*   Tsc     = (int*)  alloc((size_t)(NBG + 1) * 4);
    __hip_bfloat16* WF = (__hip_bfloat16*)alloc(20480 * 2);  // WF1|WF2|WF3
    __hip_bfloat16* A = (__hip_bfloat16*)alloc((size_t)N * 96 * 2);
    __hip_bfloat16* B = (__hip_bfloat16*)alloc((size_t)N * 96 * 2);
    __hip_bfloat16* C = (__hip_bfloat16*)alloc((size_t)N * 64 * 2);
    float* D       = (float*)alloc((size_t)(64 * 32 + 64) * 4);
    unsigned* pairs = (unsigned*)C;  // overlay, prologue only
    __hip_bfloat16* WF2 = WF + 12288;
    __hip_bfloat16* WF3 = WF + 18432;

    dim3 blk(256);
    auto cdiv = [](long long a, long long b) { return (int)((a + b - 1) / b); };

    hipMemsetAsync(D, 0, (64 * 32 + 64) * 4, stream);

    // ---- W fragment prebuild (single kernel) ----
    wfrag_all_k<<<cdiv(20480, 256), blk, 0, stream>>>(W1, W2, W3, WF);

    // ---- bucketed CSR build ----
    bucket_hist_k<<<G, blk, 0, stream>>>(dst, T, E, NB);
    int nb_scan = cdiv(NBG, 2048);
    scan_block_k<<<nb_scan, blk, 0, stream>>>(T, Tsc, bsum, NBG);
    scan_partials_k<<<1, 64, 0, stream>>>(bsum, nb_scan);
    scan_add_k<<<cdiv(NBG, 256), blk, 0, stream>>>(Tsc, bsum, NBG, E);
    bucket_scatter_k<<<G, blk, 0, stream>>>(src, dst, Tsc, pairs, E, NB);
    bucket_csr_k<<<NB, blk, 0, stream>>>(pairs, Tsc, row_ptr, dis, csr, N, E, NB, G);

    // Layer 1: 128 -> 84 (hh stride 84 -- tight rows, 12.5% less gather-line traffic;
    //                     out B bf16 stride 96 for GEMM2's 16B-aligned a-frag loads)
    gemm_mfma_v6<float, 128, 128, 84, 84, 4, 6><<<cdiv(N, 64), blk, 0, stream>>>(x, WF, dis, A, N);
    aggregate_v5<84, 84, 96, __hip_bfloat16><<<cdiv((long long)N * 21, 256), blk, 0, stream>>>(
        A, row_ptr, csr, dis, b1, B, N);

    // Layer 2: 84 -> 64 (in B bf16 stride 96; hh stride 64; out C bf16 stride 64)
    gemm_mfma_v6<__hip_bfloat16, 84, 96, 64, 64, 3, 4><<<cdiv(N, 64), blk, 0, stream>>>(B, WF2, dis, A, N);
    aggregate_v5<64, 64, 64, __hip_bfloat16><<<cdiv((long long)N * 16, 256), blk, 0, stream>>>(
        A, row_ptr, csr, dis, b2, C, N);

    // Layer 3: 64 -> 32, aggregate fused with mean-pool
    gemm_mfma_v6<__hip_bfloat16, 64, 64, 32, 32, 2, 2><<<cdiv(N, 64), blk, 0, stream>>>(C, WF3, dis, A, N);
    agg_pool_k<<<cdiv((long long)N * 8, 256), blk, 0, stream>>>(
        A, row_ptr, csr, dis, b3, bat, D, D + 64 * 32, N);

    // head
    head_k<<<1, 128, 0, stream>>>(D, D + 64 * 32, Wl, bl, (float*)d_out);
}

// Round 19
// 254.142 us; speedup vs baseline: 1.2143x; 1.0073x over previous
//
#include <hip/hip_runtime.h>
#include <hip/hip_bf16.h>

typedef __attribute__((ext_vector_type(8))) short bf16x8;
typedef __attribute__((ext_vector_type(4))) float f32x4;

__device__ inline short f2bf(float f) {
    __hip_bfloat16 h = __float2bfloat16(f);
    return *reinterpret_cast<short*>(&h);
}

// ---------------- bucketed CSR build (no global atomics) ----------------
// pairs packed: (dst&255)<<24 | src   (src < 2^24)

__global__ __launch_bounds__(256) void bucket_hist_k(
    const int* __restrict__ dst, int* __restrict__ T, int E, int NB)
{
    __shared__ int hist[512];
    for (int b = threadIdx.x; b < NB; b += 256) hist[b] = 0;
    __syncthreads();
    int per = (E + gridDim.x - 1) / gridDim.x;
    int s = blockIdx.x * per;
    int e = min(E, s + per);
    for (int i = s + threadIdx.x; i < e; i += 256)
        atomicAdd(&hist[dst[i] >> 8], 1);
    __syncthreads();
    for (int b = threadIdx.x; b < NB; b += 256)
        T[b * gridDim.x + blockIdx.x] = hist[b];
}

__global__ __launch_bounds__(256) void scan_block_k(
    const int* __restrict__ in, int* __restrict__ out,
    int* __restrict__ bsum, int n)
{
    __shared__ int ts[256];
    int base = blockIdx.x * 2048;
    int i0 = base + threadIdx.x * 8;
    int vals[8];
    int s = 0;
#pragma unroll
    for (int j = 0; j < 8; ++j) {
        int v = (i0 + j) < n ? in[i0 + j] : 0;
        vals[j] = v; s += v;
    }
    ts[threadIdx.x] = s;
    __syncthreads();
    for (int d = 1; d < 256; d <<= 1) {
        int t = (threadIdx.x >= (unsigned)d) ? ts[threadIdx.x - d] : 0;
        __syncthreads();
        ts[threadIdx.x] += t;
        __syncthreads();
    }
    int run = ts[threadIdx.x] - s;
    if (threadIdx.x == 255) bsum[blockIdx.x] = ts[255];
#pragma unroll
    for (int j = 0; j < 8; ++j) {
        if (i0 + j < n) out[i0 + j] = run;
        run += vals[j];
    }
}

__global__ void scan_partials_k(int* __restrict__ bsum, int nb) {
    if (threadIdx.x == 0 && blockIdx.x == 0) {
        int run = 0;
        for (int i = 0; i < nb; ++i) { int t = bsum[i]; bsum[i] = run; run += t; }
    }
}

__global__ void scan_add_k(int* __restrict__ rp, const int* __restrict__ bsum,
                           int n, int E)
{
    int i = blockIdx.x * blockDim.x + threadIdx.x;
    if (i < n) rp[i] += bsum[i >> 11];
    if (i == 0) rp[n] = E;
}

__global__ __launch_bounds__(256) void bucket_scatter_k(
    const int* __restrict__ src, const int* __restrict__ dst,
    const int* __restrict__ Tsc, unsigned* __restrict__ pairs, int E, int NB)
{
    __shared__ int cur[512];
    for (int b = threadIdx.x; b < NB; b += 256)
        cur[b] = Tsc[b * gridDim.x + blockIdx.x];
    __syncthreads();
    int per = (E + gridDim.x - 1) / gridDim.x;
    int s = blockIdx.x * per;
    int e = min(E, s + per);
    for (int i = s + threadIdx.x; i < e; i += 256) {
        int d = dst[i];
        int pos = atomicAdd(&cur[d >> 8], 1);
        pairs[pos] = ((unsigned)(d & 255) << 24) | (unsigned)src[i];
    }
}

__global__ __launch_bounds__(256) void bucket_csr_k(
    const unsigned* __restrict__ pairs, const int* __restrict__ Tsc,
    int* __restrict__ row_ptr, float* __restrict__ dis,
    int* __restrict__ csr, int N, int E, int NB, int G)
{
    __shared__ int cnt[256];
    __shared__ int ts[256];
    __shared__ int cur[256];
    const int b = blockIdx.x;
    const int node0 = b << 8;
    const int e0 = Tsc[b * G];
    const int e1 = Tsc[(b + 1) * G];
    const int j = threadIdx.x;
    cnt[j] = 0;
    __syncthreads();
    for (int i = e0 + j; i < e1; i += 256)
        atomicAdd(&cnt[pairs[i] >> 24], 1);
    __syncthreads();
    int c = cnt[j];
    ts[j] = c;
    __syncthreads();
    for (int d = 1; d < 256; d <<= 1) {
        int t = (j >= d) ? ts[j - d] : 0;
        __syncthreads();
        ts[j] += t;
        __syncthreads();
    }
    int excl = ts[j] - c;
    int node = node0 + j;
    if (node < N) {
        row_ptr[node] = e0 + excl;
        dis[node] = rsqrtf(1.0f + (float)c);
    }
    cur[j] = e0 + excl;
    if (b == NB - 1 && j == 0) row_ptr[N] = E;
    __syncthreads();
    for (int i = e0 + j; i < e1; i += 256) {
        unsigned p = pairs[i];
        int pos = atomicAdd(&cur[p >> 24], 1);
        csr[pos] = (int)(p & 0xFFFFFFu);
    }
}

// ---------------- W fragment prebuild: all 3 layers, one kernel ----------------

__device__ inline void wfrag_seg(const float* __restrict__ W,
                                 __hip_bfloat16* __restrict__ out, int idx,
                                 int FIN, int FOUT, int NKK)
{
    int e = idx & 7;
    int lane = (idx >> 3) & 63;
    int t = idx >> 9;
    int kk = t % NKK, nn = t / NKK;
    int col = nn * 16 + (lane & 15);
    int k = kk * 32 + (lane >> 4) * 8 + e;
    float v = (k < FIN && col < FOUT) ? W[k * FOUT + col] : 0.f;
    out[idx] = __float2bfloat16(v);
}

__global__ void wfrag_all_k(const float* __restrict__ W1,
                            const float* __restrict__ W2,
                            const float* __restrict__ W3,
                            __hip_bfloat16* __restrict__ WF)
{
    int idx = blockIdx.x * 256 + threadIdx.x;
    if (idx < 12288)       wfrag_seg(W1, WF,          idx,          128, 84, 4);
    else if (idx < 18432)  wfrag_seg(W2, WF + 12288,  idx - 12288,   84, 64, 3);
    else if (idx < 20480)  wfrag_seg(W3, WF + 18432,  idx - 18432,   64, 32, 2);
}

// ---------------- GEMM v6: MFMA, no LDS; f32 or bf16 input ----------------

template<int FIN>
__device__ inline bf16x8 load_a8f(const float* __restrict__ p, int k0) {
    bf16x8 r;
    if (k0 + 8 <= FIN) {
        float4 v0 = *reinterpret_cast<const float4*>(p + k0);
        float4 v1 = *reinterpret_cast<const float4*>(p + k0 + 4);
        r[0] = f2bf(v0.x); r[1] = f2bf(v0.y); r[2] = f2bf(v0.z); r[3] = f2bf(v0.w);
        r[4] = f2bf(v1.x); r[5] = f2bf(v1.y); r[6] = f2bf(v1.z); r[7] = f2bf(v1.w);
    } else {
#pragma unroll
        for (int e = 0; e < 8; ++e)
            r[e] = (k0 + e < FIN) ? f2bf(p[k0 + e]) : (short)0;
    }
    return r;
}

template<int FIN>
__device__ inline bf16x8 load_a8b(const __hip_bfloat16* __restrict__ p, int k0) {
    if (k0 + 8 <= FIN)
        return *reinterpret_cast<const bf16x8*>(p + k0);
    bf16x8 r;
    const short* ps = (const short*)p;
#pragma unroll
    for (int e = 0; e < 8; ++e)
        r[e] = (k0 + e < FIN) ? ps[k0 + e] : (short)0;
    return r;
}

template<typename TIN, int FIN, int SIN, int FOUT, int HS, int NKK, int CT>
__global__ __launch_bounds__(256) void gemm_mfma_v6(
    const TIN* __restrict__ in, const __hip_bfloat16* __restrict__ wfrag,
    const float* __restrict__ dis, __hip_bfloat16* __restrict__ hh, int n)
{
    const int tid = threadIdx.x;
    const long long base = (long long)blockIdx.x * 64;
    const int cnt = (int)min((long long)64, (long long)n - base);
    const int wv = tid >> 6, lane = tid & 63;
    const int rlo = lane & 15, kg = lane >> 4, kb = kg * 8;
    const int arow = wv * 16 + rlo;
    const long long row = base + arow;

    bf16x8 a[NKK];
    if (arow < cnt) {
        const TIN* p = &in[(size_t)row * SIN];
#pragma unroll
        for (int kk = 0; kk < NKK; ++kk) {
            if constexpr (sizeof(TIN) == 4)
                a[kk] = load_a8f<FIN>((const float*)p, kk * 32 + kb);
            else
                a[kk] = load_a8b<FIN>((const __hip_bfloat16*)p, kk * 32 + kb);
        }
    } else {
#pragma unroll
        for (int kk = 0; kk < NKK; ++kk)
            a[kk] = (bf16x8){0, 0, 0, 0, 0, 0, 0, 0};
    }

    f32x4 acc[CT];
#pragma unroll
    for (int nn = 0; nn < CT; ++nn) acc[nn] = (f32x4){0.f, 0.f, 0.f, 0.f};

#pragma unroll
    for (int nn = 0; nn < CT; ++nn) {
#pragma unroll
        for (int kk = 0; kk < NKK; ++kk) {
            bf16x8 b = *reinterpret_cast<const bf16x8*>(
                &wfrag[(size_t)((nn * NKK + kk) * 64 + lane) * 8]);
            acc[nn] = __builtin_amdgcn_mfma_f32_16x16x32_bf16(a[kk], b, acc[nn], 0, 0, 0);
        }
    }

    const int r0 = wv * 16 + kg * 4;
    float dv[4];
#pragma unroll
    for (int i = 0; i < 4; ++i)
        dv[i] = (r0 + i < cnt) ? dis[base + r0 + i] : 0.f;
#pragma unroll
    for (int nn = 0; nn < CT; ++nn) {
        const int col = nn * 16 + rlo;
        if (col < FOUT) {
#pragma unroll
            for (int i = 0; i < 4; ++i) {
                int r = r0 + i;
                if (r < cnt) {
                    __hip_bfloat16 o = __float2bfloat16(acc[nn][i] * dv[i]);
                    hh[(size_t)(base + r) * HS + col] = o;
                }
            }
        }
    }
}

// ---------------- CSR aggregate v5: 8-deep MLP, strided, bf16/f32 out ----------------

template<int F, int HS, int SO, typename TOUT>
__global__ __launch_bounds__(256) void aggregate_v5(
    const __hip_bfloat16* __restrict__ hh, const int* __restrict__ row_ptr,
    const int* __restrict__ csr, const float* __restrict__ dis,
    const float* __restrict__ b, TOUT* __restrict__ out, int n)
{
    constexpr int FG = F / 4;
    long long idx = (long long)blockIdx.x * 256 + threadIdx.x;
    if (idx >= (long long)n * FG) return;
    int node = (int)(idx / FG);
    int fg = (int)(idx - (long long)node * FG);
    const int bf = fg * 4;

    const unsigned short* hs = (const unsigned short*)hh;
    auto lo16 = [](unsigned u) { return __uint_as_float(u << 16); };
    auto hi16 = [](unsigned u) { return __uint_as_float(u & 0xFFFF0000u); };

    uint2 su = *reinterpret_cast<const uint2*>(&hs[(size_t)node * HS + bf]);
    float a0 = lo16(su.x), a1 = hi16(su.x), a2 = lo16(su.y), a3 = hi16(su.y);
    float c0 = 0.f, c1 = 0.f, c2 = 0.f, c3 = 0.f;

    int e = row_ptr[node];
    const int e1 = row_ptr[node + 1];
    for (; e + 8 <= e1; e += 8) {
        int s0 = csr[e],     s1 = csr[e + 1], s2 = csr[e + 2], s3 = csr[e + 3];
        int s4 = csr[e + 4], s5 = csr[e + 5], s6 = csr[e + 6], s7 = csr[e + 7];
        uint2 u0 = *reinterpret_cast<const uint2*>(&hs[(size_t)s0 * HS + bf]);
        uint2 u1 = *reinterpret_cast<const uint2*>(&hs[(size_t)s1 * HS + bf]);
        uint2 u2 = *reinterpret_cast<const uint2*>(&hs[(size_t)s2 * HS + bf]);
        uint2 u3 = *reinterpret_cast<const uint2*>(&hs[(size_t)s3 * HS + bf]);
        uint2 u4 = *reinterpret_cast<const uint2*>(&hs[(size_t)s4 * HS + bf]);
        uint2 u5 = *reinterpret_cast<const uint2*>(&hs[(size_t)s5 * HS + bf]);
        uint2 u6 = *reinterpret_cast<const uint2*>(&hs[(size_t)s6 * HS + bf]);
        uint2 u7 = *reinterpret_cast<const uint2*>(&hs[(size_t)s7 * HS + bf]);
        a0 += lo16(u0.x); a1 += hi16(u0.x); a2 += lo16(u0.y); a3 += hi16(u0.y);
        c0 += lo16(u1.x); c1 += hi16(u1.x); c2 += lo16(u1.y); c3 += hi16(u1.y);
        a0 += lo16(u2.x); a1 += hi16(u2.x); a2 += lo16(u2.y); a3 += hi16(u2.y);
        c0 += lo16(u3.x); c1 += hi16(u3.x); c2 += lo16(u3.y); c3 += hi16(u3.y);
        a0 += lo16(u4.x); a1 += hi16(u4.x); a2 += lo16(u4.y); a3 += hi16(u4.y);
        c0 += lo16(u5.x); c1 += hi16(u5.x); c2 += lo16(u5.y); c3 += hi16(u5.y);
        a0 += lo16(u6.x); a1 += hi16(u6.x); a2 += lo16(u6.y); a3 += hi16(u6.y);
        c0 += lo16(u7.x); c1 += hi16(u7.x); c2 += lo16(u7.y); c3 += hi16(u7.y);
    }
    if (e + 4 <= e1) {
        int s0 = csr[e], s1 = csr[e + 1], s2 = csr[e + 2], s3 = csr[e + 3];
        uint2 u0 = *reinterpret_cast<const uint2*>(&hs[(size_t)s0 * HS + bf]);
        uint2 u1 = *reinterpret_cast<const uint2*>(&hs[(size_t)s1 * HS + bf]);
        uint2 u2 = *reinterpret_cast<const uint2*>(&hs[(size_t)s2 * HS + bf]);
        uint2 u3 = *reinterpret_cast<const uint2*>(&hs[(size_t)s3 * HS + bf]);
        a0 += lo16(u0.x); a1 += hi16(u0.x); a2 += lo16(u0.y); a3 += hi16(u0.y);
        c0 += lo16(u1.x); c1 += hi16(u1.x); c2 += lo16(u1.y); c3 += hi16(u1.y);
        a0 += lo16(u2.x); a1 += hi16(u2.x); a2 += lo16(u2.y); a3 += hi16(u2.y);
        c0 += lo16(u3.x); c1 += hi16(u3.x); c2 += lo16(u3.y); c3 += hi16(u3.y);
        e += 4;
    }
    for (; e < e1; ++e) {
        int s = csr[e];
        uint2 u = *reinterpret_cast<const uint2*>(&hs[(size_t)s * HS + bf]);
        a0 += lo16(u.x); a1 += hi16(u.x); a2 += lo16(u.y); a3 += hi16(u.y);
    }
    a0 += c0; a1 += c1; a2 += c2; a3 += c3;

    float d = dis[node];
    float4 bb = *reinterpret_cast<const float4*>(&b[bf]);
    float r0 = fmaxf(fmaf(d, a0, bb.x), 0.0f);
    float r1 = fmaxf(fmaf(d, a1, bb.y), 0.0f);
    float r2 = fmaxf(fmaf(d, a2, bb.z), 0.0f);
    float r3 = fmaxf(fmaf(d, a3, bb.w), 0.0f);

    if constexpr (sizeof(TOUT) == 2) {
        alignas(8) __hip_bfloat16 o[4];
        o[0] = __float2bfloat16(r0);
        o[1] = __float2bfloat16(r1);
        o[2] = __float2bfloat16(r2);
        o[3] = __float2bfloat16(r3);
        *reinterpret_cast<uint2*>(&((__hip_bfloat16*)out)[(size_t)node * SO + bf]) =
            *reinterpret_cast<const uint2*>(o);
    } else {
        float4 o;
        o.x = r0; o.y = r1; o.z = r2; o.w = r3;
        *reinterpret_cast<float4*>(&((float*)out)[(size_t)node * SO + bf]) = o;
    }
}

// ---------------- layer-3 aggregate fused with mean-pool (F=32, HS=32) ----------------

__global__ __launch_bounds__(256) void agg_pool_k(
    const __hip_bfloat16* __restrict__ hh, const int* __restrict__ row_ptr,
    const int* __restrict__ csr, const float* __restrict__ dis,
    const float* __restrict__ b, const int* __restrict__ batch,
    float* __restrict__ sums, float* __restrict__ cnt, int n)
{
    __shared__ float s[64 * 32];
    __shared__ float sc[64];
    for (int i = threadIdx.x; i < 64 * 32; i += 256) s[i] = 0.0f;
    if (threadIdx.x < 64) sc[threadIdx.x] = 0.0f;
    __syncthreads();

    constexpr int HS = 32;
    long long idx = (long long)blockIdx.x * 256 + threadIdx.x;
    if (idx < (long long)n * 8) {
        int node = (int)(idx >> 3);
        int fg = (int)(idx & 7);
        const int bf = fg * 4;

        const unsigned short* hs = (const unsigned short*)hh;
        auto lo16 = [](unsigned u) { return __uint_as_float(u << 16); };
        auto hi16 = [](unsigned u) { return __uint_as_float(u & 0xFFFF0000u); };

        uint2 su = *reinterpret_cast<const uint2*>(&hs[(size_t)node * HS + bf]);
        float a0 = lo16(su.x), a1 = hi16(su.x), a2 = lo16(su.y), a3 = hi16(su.y);
        float c0 = 0.f, c1 = 0.f, c2 = 0.f, c3 = 0.f;

        int e = row_ptr[node];
        const int e1 = row_ptr[node + 1];
        for (; e + 8 <= e1; e += 8) {
            int s0 = csr[e],     s1 = csr[e + 1], s2 = csr[e + 2], s3 = csr[e + 3];
            int s4 = csr[e + 4], s5 = csr[e + 5], s6 = csr[e + 6], s7 = csr[e + 7];
            uint2 u0 = *reinterpret_cast<const uint2*>(&hs[(size_t)s0 * HS + bf]);
            uint2 u1 = *reinterpret_cast<const uint2*>(&hs[(size_t)s1 * HS + bf]);
            uint2 u2 = *reinterpret_cast<const uint2*>(&hs[(size_t)s2 * HS + bf]);
            uint2 u3 = *reinterpret_cast<const uint2*>(&hs[(size_t)s3 * HS + bf]);
            uint2 u4 = *reinterpret_cast<const uint2*>(&hs[(size_t)s4 * HS + bf]);
            uint2 u5 = *reinterpret_cast<const uint2*>(&hs[(size_t)s5 * HS + bf]);
            uint2 u6 = *reinterpret_cast<const uint2*>(&hs[(size_t)s6 * HS + bf]);
            uint2 u7 = *reinterpret_cast<const uint2*>(&hs[(size_t)s7 * HS + bf]);
            a0 += lo16(u0.x); a1 += hi16(u0.x); a2 += lo16(u0.y); a3 += hi16(u0.y);
            c0 += lo16(u1.x); c1 += hi16(u1.x); c2 += lo16(u1.y); c3 += hi16(u1.y);
            a0 += lo16(u2.x); a1 += hi16(u2.x); a2 += lo16(u2.y); a3 += hi16(u2.y);
            c0 += lo16(u3.x); c1 += hi16(u3.x); c2 += lo16(u3.y); c3 += hi16(u3.y);
            a0 += lo16(u4.x); a1 += hi16(u4.x); a2 += lo16(u4.y); a3 += hi16(u4.y);
            c0 += lo16(u5.x); c1 += hi16(u5.x); c2 += lo16(u5.y); c3 += hi16(u5.y);
            a0 += lo16(u6.x); a1 += hi16(u6.x); a2 += lo16(u6.y); a3 += hi16(u6.y);
            c0 += lo16(u7.x); c1 += hi16(u7.x); c2 += lo16(u7.y); c3 += hi16(u7.y);
        }
        if (e + 4 <= e1) {
            int s0 = csr[e], s1 = csr[e + 1], s2 = csr[e + 2], s3 = csr[e + 3];
            uint2 u0 = *reinterpret_cast<const uint2*>(&hs[(size_t)s0 * HS + bf]);
            uint2 u1 = *reinterpret_cast<const uint2*>(&hs[(size_t)s1 * HS + bf]);
            uint2 u2 = *reinterpret_cast<const uint2*>(&hs[(size_t)s2 * HS + bf]);
            uint2 u3 = *reinterpret_cast<const uint2*>(&hs[(size_t)s3 * HS + bf]);
            a0 += lo16(u0.x); a1 += hi16(u0.x); a2 += lo16(u0.y); a3 += hi16(u0.y);
            c0 += lo16(u1.x); c1 += hi16(u1.x); c2 += lo16(u1.y); c3 += hi16(u1.y);
            a0 += lo16(u2.x); a1 += hi16(u2.x); a2 += lo16(u2.y); a3 += hi16(u2.y);
            c0 += lo16(u3.x); c1 += hi16(u3.x); c2 += lo16(u3.y); c3 += hi16(u3.y);
            e += 4;
        }
        for (; e < e1; ++e) {
            int sx = csr[e];
            uint2 u = *reinterpret_cast<const uint2*>(&hs[(size_t)sx * HS + bf]);
            a0 += lo16(u.x); a1 += hi16(u.x); a2 += lo16(u.y); a3 += hi16(u.y);
        }
        a0 += c0; a1 += c1; a2 += c2; a3 += c3;

        float d = dis[node];
        float4 bb = *reinterpret_cast<const float4*>(&b[bf]);
        float r0 = fmaxf(fmaf(d, a0, bb.x), 0.0f);
        float r1 = fmaxf(fmaf(d, a1, bb.y), 0.0f);
        float r2 = fmaxf(fmaf(d, a2, bb.z), 0.0f);
        float r3 = fmaxf(fmaf(d, a3, bb.w), 0.0f);

        int g = batch[node];
        atomicAdd(&s[g * 32 + bf + 0], r0);
        atomicAdd(&s[g * 32 + bf + 1], r1);
        atomicAdd(&s[g * 32 + bf + 2], r2);
        atomicAdd(&s[g * 32 + bf + 3], r3);
        if (fg == 0) atomicAdd(&sc[g], 1.0f);
    }
    __syncthreads();
    for (int i = threadIdx.x; i < 64 * 32; i += 256) {
        float v = s[i];
        if (v != 0.0f) atomicAdd(&sums[i], v);
    }
    if (threadIdx.x < 64) {
        float v = sc[threadIdx.x];
        if (v != 0.0f) atomicAdd(&cnt[threadIdx.x], v);
    }
}

__global__ void head_k(const float* __restrict__ sums, const float* __restrict__ cnt,
                       const float* __restrict__ Wl, const float* __restrict__ bl,
                       float* __restrict__ out)
{
    int tid = threadIdx.x;
    if (tid < 128) {
        int g = tid >> 1;
        int o = tid & 1;
        float c = fmaxf(cnt[g], 1.0f);
        float a = 0.0f;
#pragma unroll
        for (int f = 0; f < 32; ++f)
            a += (sums[g * 32 + f] / c) * Wl[f * 2 + o];
        out[tid] = a + bl[o];
    }
}

// ---------------- launch ----------------

extern "C" void kernel_launch(void* const* d_in, const int* in_sizes, int n_in,
                              void* d_out, int out_size, void* d_ws, size_t ws_size,
                              hipStream_t stream)
{
    const float* x   = (const float*)d_in[0];
    const int*   ei  = (const int*)d_in[1];
    const int*   bat = (const int*)d_in[2];
    const float* W1  = (const float*)d_in[3];
    const float* b1  = (const float*)d_in[4];
    const float* W2  = (const float*)d_in[5];
    const float* b2  = (const float*)d_in[6];
    const float* W3  = (const float*)d_in[7];
    const float* b3  = (const float*)d_in[8];
    const float* Wl  = (const float*)d_in[9];
    const float* bl  = (const float*)d_in[10];

    const int N = in_sizes[0] / 128;
    const int E = in_sizes[1] / 2;
    const int* src = ei;
    const int* dst = ei + E;

    const int NB = (N + 255) >> 8;
    const int G  = 256;              // hist/scatter blocks (all CUs busy)
    const int NBG = NB * G;

    char* ws = (char*)d_ws;
    size_t off = 0;
    auto alloc = [&](size_t bytes) -> char* {
        char* p = ws + off;
        off += (bytes + 255) & ~(size_t)255;
        return p;
    };
    float* dis     = (float*)alloc((size_t)N * 4);
    int*   row_ptr = (int*)  alloc((size_t)(N + 1) * 4);
    int*   bsum    = (int*)  alloc(256 * 4);
    int*   csr     = (int*)  alloc((size_t)E * 4);
    int*   T       = (int*)  alloc((size_t)NBG * 4);
    int*   Tsc     = (int*)  alloc((size_t)(NBG + 1) * 4);
    __hip_bfloat16* WF = (__hip_bfloat16*)alloc(20480 * 2);  // WF1|WF2|WF3
    __hip_bfloat16* A = (__hip_bfloat16*)alloc((size_t)N * 96 * 2);
    __hip_bfloat16* B = (__hip_bfloat16*)alloc((size_t)N * 96 * 2);
    __hip_bfloat16* C = (__hip_bfloat16*)alloc((size_t)N * 64 * 2);
    float* D       = (float*)alloc((size_t)(64 * 32 + 64) * 4);
    unsigned* pairs = (unsigned*)C;  // overlay, prologue only
    __hip_bfloat16* WF2 = WF + 12288;
    __hip_bfloat16* WF3 = WF + 18432;

    dim3 blk(256);
    auto cdiv = [](long long a, long long b) { return (int)((a + b - 1) / b); };

    hipMemsetAsync(D, 0, (64 * 32 + 64) * 4, stream);

    // ---- W fragment prebuild (single kernel) ----
    wfrag_all_k<<<cdiv(20480, 256), blk, 0, stream>>>(W1, W2, W3, WF);

    // ---- bucketed CSR build ----
    bucket_hist_k<<<G, blk, 0, stream>>>(dst, T, E, NB);
    int nb_scan = cdiv(NBG, 2048);
    scan_block_k<<<nb_scan, blk, 0, stream>>>(T, Tsc, bsum, NBG);
    scan_partials_k<<<1, 64, 0, stream>>>(bsum, nb_scan);
    scan_add_k<<<cdiv(NBG, 256), blk, 0, stream>>>(Tsc, bsum, NBG, E);
    bucket_scatter_k<<<G, blk, 0, stream>>>(src, dst, Tsc, pairs, E, NB);
    bucket_csr_k<<<NB, blk, 0, stream>>>(pairs, Tsc, row_ptr, dis, csr, N, E, NB, G);

    // Layer 1: 128 -> 84 (hh stride 96: 192B line-aligned rows = exactly 3 lines/gather;
    //                     stride 84 measured WORSE -- 168B rows straddle ~3.6 lines)
    gemm_mfma_v6<float, 128, 128, 84, 96, 4, 6><<<cdiv(N, 64), blk, 0, stream>>>(x, WF, dis, A, N);
    aggregate_v5<84, 96, 96, __hip_bfloat16><<<cdiv((long long)N * 21, 256), blk, 0, stream>>>(
        A, row_ptr, csr, dis, b1, B, N);

    // Layer 2: 84 -> 64 (in B bf16 stride 96; hh stride 64; out C bf16 stride 64)
    gemm_mfma_v6<__hip_bfloat16, 84, 96, 64, 64, 3, 4><<<cdiv(N, 64), blk, 0, stream>>>(B, WF2, dis, A, N);
    aggregate_v5<64, 64, 64, __hip_bfloat16><<<cdiv((long long)N * 16, 256), blk, 0, stream>>>(
        A, row_ptr, csr, dis, b2, C, N);

    // Layer 3: 64 -> 32, aggregate fused with mean-pool
    gemm_mfma_v6<__hip_bfloat16, 64, 64, 32, 32, 2, 2><<<cdiv(N, 64), blk, 0, stream>>>(C, WF3, dis, A, N);
    agg_pool_k<<<cdiv((long long)N * 8, 256), blk, 0, stream>>>(
        A, row_ptr, csr, dis, b3, bat, D, D + 64 * 32, N);

    // head
    head_k<<<1, 128, 0, stream>>>(D, D + 64 * 32, Wl, bl, (float*)d_out);
}